// Round 8
// baseline (984.799 us; speedup 1.0000x reference)
//
#include <hip/hip_runtime.h>
#include <math.h>

#define S 4096
#define H 1024
#define FF 3072
#define G 100
#define MAXSPAN 30
#define MAXK 819
#define NBAND (S * MAXSPAN)   // 122880 slots, 122445 valid
#define BAND_COUNT 122445.0

// out layout (float32)
#define O_START 0
#define O_END   819
#define O_MASK  1638
#define O_SEQ   2457
#define O_COST  (2457 + S * H)   // 4196761

typedef __bf16 bf16x8 __attribute__((ext_vector_type(8)));
typedef float f32x16 __attribute__((ext_vector_type(16)));

// ---------------- helpers ----------------

__device__ __forceinline__ float block_reduce_256(float x, volatile float* red) {
  #pragma unroll
  for (int off = 32; off > 0; off >>= 1) x += __shfl_down(x, off, 64);
  int wid = threadIdx.x >> 6;
  int lane = threadIdx.x & 63;
  __syncthreads();
  if (lane == 0) red[wid] = x;
  __syncthreads();
  return red[0] + red[1] + red[2] + red[3];
}

__device__ __forceinline__ float block_reduce_1024(float x, volatile float* red) {
  #pragma unroll
  for (int off = 32; off > 0; off >>= 1) x += __shfl_down(x, off, 64);
  int wid = threadIdx.x >> 6;   // 0..15
  int lane = threadIdx.x & 63;
  __syncthreads();
  if (lane == 0) red[wid] = x;
  __syncthreads();
  float s = 0.f;
  #pragma unroll
  for (int q = 0; q < 16; q++) s += red[q];
  return s;
}

__device__ __forceinline__ unsigned f2key(float f) {
  unsigned b = __float_as_uint(f);
  return (b & 0x80000000u) ? ~b : (b | 0x80000000u);
}

__device__ __forceinline__ unsigned short bf16_rne(float x) {
  unsigned u = __float_as_uint(x);
  unsigned r = ((u >> 16) & 1u) + 0x7FFFu;
  return (unsigned short)((u + r) >> 16);
}

__device__ __forceinline__ void split2(float x, unsigned short& h, unsigned short& l) {
  h = bf16_rne(x);
  float hf = __uint_as_float(((unsigned)h) << 16);
  l = bf16_rne(x - hf);
}

__device__ __forceinline__ void gld16(const void* g, void* l) {
  __builtin_amdgcn_global_load_lds(
      (const __attribute__((address_space(1))) unsigned int*)g,
      (__attribute__((address_space(3))) unsigned int*)l, 16, 0, 0);
}

// ---------------- pack bodies: f32 -> hi/lo bf16, tiled [panel][kq][r][8] ----------------
// tiled element offset = panel*(128*K) + kq*1024 + r*8 + s   (panel = row/128, kq = k/8)

__device__ __forceinline__ void pack_a_body(const float* __restrict__ A,
                                            float* __restrict__ Aout,   // optional passthrough copy
                                            unsigned short* __restrict__ hi,
                                            unsigned short* __restrict__ lo,
                                            int K, int bx, int by) {
  __shared__ float tile[32][33];
  const int t = threadIdx.x;
  const int tx = t & 31, ty8 = t >> 5;
  const int k0 = bx * 32, r0 = by * 32;
  #pragma unroll
  for (int r = ty8; r < 32; r += 8) {
    float v = A[(size_t)(r0 + r) * K + k0 + tx];
    tile[r][tx] = v;
    if (Aout) Aout[(size_t)(r0 + r) * K + k0 + tx] = v;
  }
  __syncthreads();
  if (t < 128) {
    const int kql = t >> 5;
    const int rl = t & 31;
    unsigned short h8[8], l8[8];
    #pragma unroll
    for (int s = 0; s < 8; s++) split2(tile[rl][kql * 8 + s], h8[s], l8[s]);
    const size_t panel = (size_t)(r0 >> 7);
    const int rloc = (r0 & 127) + rl;
    const size_t off = panel * (size_t)(128 * K) + (size_t)(k0 / 8 + kql) * 1024 + (size_t)rloc * 8;
    *(uint4*)(hi + off) = *(const uint4*)h8;
    *(uint4*)(lo + off) = *(const uint4*)l8;
  }
}

__device__ __forceinline__ void pack_bt_body(const float* __restrict__ W,
                                             unsigned short* __restrict__ hi,
                                             unsigned short* __restrict__ lo,
                                             int K, int N, int bx, int by) {
  __shared__ float tile[32][33];   // tile[k_local][n_local]
  const int t = threadIdx.x;
  const int tx = t & 31, ty8 = t >> 5;
  const int k0 = bx * 32, n0 = by * 32;
  #pragma unroll
  for (int r = ty8; r < 32; r += 8)
    tile[r][tx] = W[(size_t)(k0 + r) * N + n0 + tx];
  __syncthreads();
  if (t < 128) {
    const int kql = t >> 5;
    const int nl = t & 31;
    unsigned short h8[8], l8[8];
    #pragma unroll
    for (int s = 0; s < 8; s++) split2(tile[kql * 8 + s][nl], h8[s], l8[s]);
    const size_t panel = (size_t)(n0 >> 7);
    const int nloc = (n0 & 127) + nl;
    const size_t off = panel * (size_t)(128 * K) + (size_t)(k0 / 8 + kql) * 1024 + (size_t)nloc * 8;
    *(uint4*)(hi + off) = *(const uint4*)h8;
    *(uint4*)(lo + off) = *(const uint4*)l8;
  }
}

// head pack: seq (+passthrough to out) and both H x FF weights in one dispatch.
// grid (32, 320): y<128 -> pack_a(seq); y<224 -> W_sm; else W_em
__global__ __launch_bounds__(256) void pack_head_kernel(const float* __restrict__ seq,
                                                        float* __restrict__ seq_out,
                                                        unsigned short* __restrict__ sh,
                                                        unsigned short* __restrict__ sl,
                                                        const float* __restrict__ W1,
                                                        const float* __restrict__ W2,
                                                        unsigned short* __restrict__ w1h,
                                                        unsigned short* __restrict__ w1l,
                                                        unsigned short* __restrict__ w2h,
                                                        unsigned short* __restrict__ w2l) {
  const int y = blockIdx.y;
  if (y < 128)      pack_a_body(seq, seq_out, sh, sl, H, blockIdx.x, y);
  else if (y < 224) pack_bt_body(W1, w1h, w1l, H, FF, blockIdx.x, y - 128);
  else              pack_bt_body(W2, w2h, w2l, H, FF, blockIdx.x, y - 224);
}

// mid pack (v8: W_s2e only — LN-A pack fused into ln_stats). grid (96, 96)
__global__ __launch_bounds__(256) void pack_mid_kernel(const float* __restrict__ Ws2e,
                                                       unsigned short* __restrict__ wbh,
                                                       unsigned short* __restrict__ wbl) {
  pack_bt_body(Ws2e, wbh, wbl, FF, FF, blockIdx.x, blockIdx.y);
}

// ---------------- MFMA GEMM core v7 (kept — at plain-HIP structural level) ----------------
// 256x192 block tile, 4 waves (256 thr), each owning 128x96 output; 4 LDS slots,
// counted-vmcnt prefetch distance 3. Per-acc product order hh->lh->hl — bitwise
// identical output across all versions.
//
// LDS slot layout (28672 B): Ah [2kq][256r][8]e = 8192 | Al 8192 | Bh [2kq][192n][8] 6144 | Bl 6144
#define SLOTB 28672
#define A_STR 8192
#define B_BASE 16384
#define B_STR 6144

template <int EPI>
__device__ __forceinline__ void gemm8_body(const char* __restrict__ cAh, const char* __restrict__ cAl,
                                           const char* __restrict__ cBh, const char* __restrict__ cBl,
                                           const float* __restrict__ bias,
                                           float* __restrict__ C,
                                           int bm, int bn, int N, int K,
                                           char* smem) {
  const int tid = threadIdx.x;
  const int lane = tid & 63;
  const int wid = __builtin_amdgcn_readfirstlane(tid >> 6);   // 0..3
  const int wm = wid >> 1, wn = wid & 1;         // 2 x 2 wave grid (128 x 96 per wave)
  const int khalf = lane >> 5;
  const int r31 = lane & 31;
  const size_t PS = (size_t)256 * (size_t)K;     // bytes per 128-row packed panel

  // per-wave stage descriptors: 7 loads each for waves 0..3 (28 loads per 16-k slot)
  const char* lsrc[7];
  int ldst[7];
  #pragma unroll
  for (int i = 0; i < 7; i++) {
    int q = wid * 7 + i;   // 0..27
    if (q < 16) {          // A: 2 streams x 2 kq x 4 row-units(64)
      int str = q >> 3, r = q & 7, kql = r >> 2, u = r & 3;
      lsrc[i] = (str ? cAl : cAh) + (size_t)((bm >> 7) + (u >> 1)) * PS
              + (size_t)(kql * 2048 + (u & 1) * 1024 + lane * 16);
      ldst[i] = str * A_STR + kql * 4096 + u * 1024;
    } else {               // B: 2 streams x 2 kq x 3 col-units(64)
      int qq = q - 16;
      int str = qq / 6, r = qq % 6, kql = r / 3, v = r % 3;
      int gcol = bn + 64 * v;
      lsrc[i] = (str ? cBl : cBh) + (size_t)(gcol >> 7) * PS
              + (size_t)(kql * 2048 + ((gcol >> 6) & 1) * 1024 + lane * 16);
      ldst[i] = B_BASE + str * B_STR + kql * 3072 + v * 1024;
    }
  }

  const int aoff = khalf * 4096 + (wm * 128 + r31) * 16;
  const int boff = B_BASE + khalf * 3072 + (wn * 96 + r31) * 16;

  f32x16 acc[4][3];
  #pragma unroll
  for (int mt = 0; mt < 4; mt++)
    #pragma unroll
    for (int nt = 0; nt < 3; nt++)
      #pragma unroll
      for (int r = 0; r < 16; r++) acc[mt][nt][r] = 0.0f;

  auto stage = [&](int h) {
    char* sb = smem + (h & 3) * SLOTB;
    const size_t ko = (size_t)h * 4096;   // 2 kq per slot
    #pragma unroll
    for (int i = 0; i < 7; i++) gld16(lsrc[i] + ko, sb + ldst[i]);
  };

  const int NH = K >> 4;   // phases (16 k each); NH >= 4 for all call sites

  // prologue: slots 0,1,2 staged (21 outstanding); slot 0 complete after vmcnt(14)
  stage(0); stage(1); stage(2);
  asm volatile("s_waitcnt vmcnt(14)" ::: "memory");
  __builtin_amdgcn_s_barrier();

  for (int p = 0; p < NH; ++p) {
    const char* sm = smem + (p & 3) * SLOTB;
    bf16x8 ah[4], al[4], bh[3], bl[3];
    // hh operands first: hh MFMAs start after 7 reads; al/bl drain underneath
    // (compiler counted lgkmcnt — no explicit drain).
    #pragma unroll
    for (int mt = 0; mt < 4; mt++) ah[mt] = *(const bf16x8*)(sm + aoff + mt * 512);
    #pragma unroll
    for (int nt = 0; nt < 3; nt++) bh[nt] = *(const bf16x8*)(sm + boff + nt * 512);
    #pragma unroll
    for (int mt = 0; mt < 4; mt++) al[mt] = *(const bf16x8*)(sm + A_STR + aoff + mt * 512);
    #pragma unroll
    for (int nt = 0; nt < 3; nt++) bl[nt] = *(const bf16x8*)(sm + B_STR + boff + nt * 512);
    if (p + 3 < NH) stage(p + 3);
    __builtin_amdgcn_s_setprio(1);
    // per-acc product order hh -> lh -> hl (bitwise identical to v1..v6)
    #pragma unroll
    for (int mt = 0; mt < 4; mt++)
      #pragma unroll
      for (int nt = 0; nt < 3; nt++) {
        acc[mt][nt] = __builtin_amdgcn_mfma_f32_32x32x16_bf16(ah[mt], bh[nt], acc[mt][nt], 0, 0, 0);
        acc[mt][nt] = __builtin_amdgcn_mfma_f32_32x32x16_bf16(al[mt], bh[nt], acc[mt][nt], 0, 0, 0);
        acc[mt][nt] = __builtin_amdgcn_mfma_f32_32x32x16_bf16(ah[mt], bl[nt], acc[mt][nt], 0, 0, 0);
      }
    __builtin_amdgcn_s_setprio(0);
    // counted wait: slot p+1 (7 loads/wave) must be complete after the barrier;
    // later slots' loads stay in flight (never drain to 0 in steady state).
    if (p + 3 < NH)      { asm volatile("s_waitcnt vmcnt(14)" ::: "memory"); }
    else if (p + 2 < NH) { asm volatile("s_waitcnt vmcnt(7)" ::: "memory"); }
    else if (p + 1 < NH) { asm volatile("s_waitcnt vmcnt(0)" ::: "memory"); }
    if (p + 1 < NH) __builtin_amdgcn_s_barrier();
  }

  #pragma unroll
  for (int mt = 0; mt < 4; mt++) {
    #pragma unroll
    for (int nt = 0; nt < 3; nt++) {
      const int colg = bn + wn * 96 + nt * 32 + r31;
      const float bb = bias[colg];
      #pragma unroll
      for (int reg = 0; reg < 16; reg++) {
        const int rowl = (reg & 3) + 8 * (reg >> 2) + 4 * khalf;
        const int rowg = bm + wm * 128 + mt * 32 + rowl;
        float v = acc[mt][nt][reg] + bb;
        if (EPI == 1) v = 0.5f * v * (1.0f + erff(v * 0.70710678118654752f));
        C[(size_t)rowg * N + colg] = v;
      }
    }
  }
}

// XCD chunk swizzle for the fixed 16x16 block grid: 8 chunks of 4bx x 8by.
__device__ __forceinline__ void grid_swizzle_16x16(int& bx, int& by) {
  const int lin = blockIdx.y * 16 + blockIdx.x;
  const int X = lin & 7, c = lin >> 3;
  bx = (X & 3) * 4 + (c & 3);
  by = (X >> 2) * 8 + (c >> 2);
}

// GEMM3: single output. grid (16,16), 256 threads
__global__ __launch_bounds__(256, 1) void gemm_mfma_kernel(const unsigned short* __restrict__ Ahi,
                                                           const unsigned short* __restrict__ Alo,
                                                           const unsigned short* __restrict__ Bhi,
                                                           const unsigned short* __restrict__ Blo,
                                                           const float* __restrict__ bias,
                                                           float* __restrict__ C,
                                                           int N, int K) {
  __shared__ __align__(16) char smem[4 * SLOTB];
  int bx, by;
  grid_swizzle_16x16(bx, by);
  gemm8_body<0>((const char*)Ahi, (const char*)Alo,
                (const char*)Bhi, (const char*)Blo,
                bias, C, by * 256, bx * 192, N, K, smem);
}

// GEMM1+2 fused: blockIdx.z picks branch (same A), gelu epilogue. grid (16,16,2), 256 threads
__global__ __launch_bounds__(256, 1) void gemm_mfma_dual_kernel(const unsigned short* __restrict__ Ahi,
                                                                const unsigned short* __restrict__ Alo,
                                                                const unsigned short* __restrict__ B1hi,
                                                                const unsigned short* __restrict__ B1lo,
                                                                const unsigned short* __restrict__ B2hi,
                                                                const unsigned short* __restrict__ B2lo,
                                                                const float* __restrict__ bias1,
                                                                const float* __restrict__ bias2,
                                                                float* __restrict__ C1,
                                                                float* __restrict__ C2,
                                                                int N, int K) {
  __shared__ __align__(16) char smem[4 * SLOTB];
  const int zb = blockIdx.z;
  const unsigned short* Bhi = zb ? B2hi : B1hi;
  const unsigned short* Blo = zb ? B2lo : B1lo;
  const float* bias = zb ? bias2 : bias1;
  float* C = zb ? C2 : C1;
  int bx, by;
  grid_swizzle_16x16(bx, by);
  gemm8_body<1>((const char*)Ahi, (const char*)Alo,
                (const char*)Bhi, (const char*)Blo,
                bias, C, by * 256, bx * 192, N, K, smem);
}

// ---------------- LN stats + logit + fused LN-A pack (start branch) ----------------
// grid (S, 2): y=0 start branch (packs a3hi/a3lo), y=1 end branch (stats only).
// The pack writes the SAME bytes the old pack_mid wrote (same split2, same mu/rstd,
// same expression order) — bitwise identical; saves a full 50MB re-read of bufS.

__global__ __launch_bounds__(256) void ln_stats_kernel(const float* __restrict__ HbS,
                                                       const float* __restrict__ HbE,
                                                       const float* __restrict__ gS,
                                                       const float* __restrict__ betaS,
                                                       const float* __restrict__ wS,
                                                       const float* __restrict__ bS,
                                                       const float* __restrict__ gE,
                                                       const float* __restrict__ betaE,
                                                       const float* __restrict__ wE,
                                                       const float* __restrict__ bE,
                                                       float* __restrict__ slog,
                                                       float* __restrict__ elog,
                                                       float* __restrict__ muS,
                                                       float* __restrict__ rstdS,
                                                       float* __restrict__ muE,
                                                       float* __restrict__ rstdE,
                                                       unsigned short* __restrict__ a3hi,
                                                       unsigned short* __restrict__ a3lo) {
  __shared__ float red[4];
  const int row = blockIdx.x, tid = threadIdx.x;
  const int br = blockIdx.y;
  const float* Hb = br ? HbE : HbS;
  const float* g = br ? gE : gS;
  const float* beta = br ? betaE : betaS;
  const float* w = br ? wE : wS;
  const float* bsc = br ? bE : bS;
  const float* h = Hb + (size_t)row * FF;

  float4 v[3];
  float s = 0.0f;
  #pragma unroll
  for (int t = 0; t < 3; t++) {
    v[t] = *(const float4*)(h + tid * 4 + t * 1024);
    s += v[t].x + v[t].y + v[t].z + v[t].w;
  }
  float mu = block_reduce_256(s, red) * (1.0f / (float)FF);

  float s2 = 0.0f;
  #pragma unroll
  for (int t = 0; t < 3; t++) {
    float dx = v[t].x - mu, dy = v[t].y - mu, dz = v[t].z - mu, dw = v[t].w - mu;
    s2 += dx * dx + dy * dy + dz * dz + dw * dw;
  }
  float var = block_reduce_256(s2, red) * (1.0f / (float)FF);
  float rstd = rsqrtf(var + 1e-5f);

  float4 nv[3];
  float dot = 0.0f;
  #pragma unroll
  for (int t = 0; t < 3; t++) {
    int idx = tid * 4 + t * 1024;
    float4 gv = *(const float4*)(g + idx);
    float4 bv = *(const float4*)(beta + idx);
    float4 wv = *(const float4*)(w + idx);
    float rx = (v[t].x - mu) * rstd * gv.x + bv.x;
    float ry = (v[t].y - mu) * rstd * gv.y + bv.y;
    float rz = (v[t].z - mu) * rstd * gv.z + bv.z;
    float rw = (v[t].w - mu) * rstd * gv.w + bv.w;
    nv[t] = make_float4(rx, ry, rz, rw);
    dot += rx * wv.x + ry * wv.y + rz * wv.z + rw * wv.w;
  }
  float dt = block_reduce_256(dot, red);
  if (tid == 0) {
    if (br) { elog[row] = dt + bsc[0]; muE[row] = mu; rstdE[row] = rstd; }
    else    { slog[row] = dt + bsc[0]; muS[row] = mu; rstdS[row] = rstd; }
  }

  if (br == 0) {
    // fused LN-A pack: thread pair (2m, 2m+1) holds cols 8m..8m+7 of each 1024-block
    const size_t panel = (size_t)(row >> 7);
    const int rloc = row & 127;
    #pragma unroll
    for (int t = 0; t < 3; t++) {
      float o0 = __shfl_xor(nv[t].x, 1, 64);
      float o1 = __shfl_xor(nv[t].y, 1, 64);
      float o2 = __shfl_xor(nv[t].z, 1, 64);
      float o3 = __shfl_xor(nv[t].w, 1, 64);
      if ((tid & 1) == 0) {
        float f8[8] = {nv[t].x, nv[t].y, nv[t].z, nv[t].w, o0, o1, o2, o3};
        unsigned short h8[8], l8[8];
        #pragma unroll
        for (int q = 0; q < 8; q++) split2(f8[q], h8[q], l8[q]);
        const int kq = t * 128 + (tid >> 1);
        const size_t off = panel * (size_t)(128 * FF) + (size_t)kq * 1024 + (size_t)rloc * 8;
        *(uint4*)(a3hi + off) = *(const uint4*)h8;
        *(uint4*)(a3lo + off) = *(const uint4*)l8;
      }
    }
  }
}

// ---------------- band joint (inline E-LayerNorm, fused junk sum + 16-bit key histogram) ----------------

__global__ __launch_bounds__(256) void band_joint_kernel(const float* __restrict__ T,
                                                         const float* __restrict__ Eraw,
                                                         const float* __restrict__ muE,
                                                         const float* __restrict__ rstdE,
                                                         const float* __restrict__ gE,
                                                         const float* __restrict__ betaE,
                                                         const float* __restrict__ sl,
                                                         const float* __restrict__ el,
                                                         float* __restrict__ band,
                                                         double* __restrict__ jacc,
                                                         unsigned* __restrict__ hist16) {
  __shared__ float Elds[45][260];   // 260 = 256 + 4 pad
  __shared__ float red[4];
  const int t = threadIdx.x;
  const int bx = blockIdx.x;
  const int sbx = (bx & 7) * 32 + (bx >> 3);   // XCD-locality swizzle (perf heuristic)
  const int i0 = sbx * 16;
  const int r_l = t >> 4, c = t & 15;

  float accd[MAXSPAN];
  #pragma unroll
  for (int d = 0; d < MAXSPAN; d++) accd[d] = 0.0f;

  for (int k0 = 0; k0 < FF; k0 += 256) {
    const float* trow = T + (size_t)(i0 + r_l) * FF + k0 + c * 16;
    float4 tv0 = *(const float4*)(trow + 0);
    float4 tv1 = *(const float4*)(trow + 4);
    float4 tv2 = *(const float4*)(trow + 8);
    float4 tv3 = *(const float4*)(trow + 12);
    __syncthreads();
    for (int rr = t >> 6; rr < 45; rr += 4) {
      int gr = i0 + rr;
      int cc = (t & 63) * 4;
      float4 rv = {0.f, 0.f, 0.f, 0.f};
      if (gr < S) {
        float4 ev = *(const float4*)(Eraw + (size_t)gr * FF + k0 + cc);
        float m = muE[gr], rs = rstdE[gr];
        float4 gv = *(const float4*)(gE + k0 + cc);
        float4 bv = *(const float4*)(betaE + k0 + cc);
        rv.x = (ev.x - m) * rs * gv.x + bv.x;
        rv.y = (ev.y - m) * rs * gv.y + bv.y;
        rv.z = (ev.z - m) * rs * gv.z + bv.z;
        rv.w = (ev.w - m) * rs * gv.w + bv.w;
      }
      *(float4*)&Elds[rr][cc] = rv;
    }
    __syncthreads();
    #pragma unroll
    for (int d = 0; d < MAXSPAN; d++) {
      const float* er = &Elds[r_l + d][c * 16];
      float4 e0 = *(const float4*)(er + 0);
      float4 e1 = *(const float4*)(er + 4);
      float4 e2 = *(const float4*)(er + 8);
      float4 e3 = *(const float4*)(er + 12);
      accd[d] += tv0.x * e0.x + tv0.y * e0.y + tv0.z * e0.z + tv0.w * e0.w
               + tv1.x * e1.x + tv1.y * e1.y + tv1.z * e1.z + tv1.w * e1.w
               + tv2.x * e2.x + tv2.y * e2.y + tv2.z * e2.z + tv2.w * e2.w
               + tv3.x * e3.x + tv3.y * e3.y + tv3.z * e3.z + tv3.w * e3.w;
    }
  }

  const int i = i0 + r_l;
  const float my_sl = sl[i];
  float jsum = 0.0f;
  #pragma unroll
  for (int d = 0; d < MAXSPAN; d++) {
    float v = accd[d];
    v += __shfl_down(v, 8, 16);
    v += __shfl_down(v, 4, 16);
    v += __shfl_down(v, 2, 16);
    v += __shfl_down(v, 1, 16);
    if (c == 0) {
      int j = i + d;
      if (j < S) {
        float vv = v + my_sl + el[j];
        vv = fminf(fmaxf(vv, -10000.0f), 10000.0f);
        band[i * MAXSPAN + d] = vv;
        atomicAdd(&hist16[f2key(vv) >> 16], 1u);
        float p = 1.0f / (1.0f + expf(-vv));
        jsum += fmaxf(logf(1.0f - p), -100.0f);
      } else {
        band[i * MAXSPAN + d] = -1e30f;
      }
    }
  }
  float tot = block_reduce_256(jsum, red);
  if (t == 0) atomicAdd(jacc, (double)tot);
}

// ---------------- top-k + cost finalize (single block; v8: parallelized) ----------------
// v8: (a) uint4 histogram sum, (b) LDS-staged threshold-bin scan, (c) parallel
// bitonic sort of the threshold-tie set (was serial tid0 insertion sort, O(n^2)
// with up to 256 ties). Selection semantics identical: descending full-key,
// ties ascending index.

__global__ __launch_bounds__(1024) void topk_finalize_kernel(const float* __restrict__ band,
                                                             const int* __restrict__ gold,
                                                             const double* __restrict__ jacc,
                                                             const unsigned* __restrict__ hist16,
                                                             float* __restrict__ out) {
  __shared__ int csum[1024];
  __shared__ unsigned sh_T16;
  __shared__ int sh_remk;
  __shared__ int sh_chunk, sh_above;
  __shared__ unsigned hbin[64];
  __shared__ int idxbuf[1024];
  __shared__ unsigned tkey[256];
  __shared__ int tidx[256];
  __shared__ int cnt_gt, cnt_eq;
  __shared__ int sb[1024];
  __shared__ int gcell[G];
  __shared__ float redf[16];
  const int tid = threadIdx.x;

  // ---- threshold from 65536-bin histogram (vectorized sum) ----
  int s = 0;
  {
    const uint4* hv = (const uint4*)hist16 + (size_t)tid * 16;
    #pragma unroll
    for (int q = 0; q < 16; q++) {
      uint4 u = hv[q];
      s += (int)(u.x + u.y + u.z + u.w);
    }
  }
  csum[tid] = s;
  if (tid < 256) { tkey[tid] = 0u; tidx[tid] = 0x7FFFFFFF; }   // padding for bitonic
  __syncthreads();
  // suffix sum (Hillis-Steele): csum[t] = sum over chunks >= t
  for (int off = 1; off < 1024; off <<= 1) {
    int v = (tid + off < 1024) ? csum[tid + off] : 0;
    __syncthreads();
    csum[tid] += v;
    __syncthreads();
  }
  // csum non-increasing; find chunk containing the rank-MAXK crossing
  {
    int nxt = (tid < 1023) ? csum[tid + 1] : 0;
    if (csum[tid] >= MAXK && nxt < MAXK) { sh_chunk = tid; sh_above = nxt; }
  }
  __syncthreads();
  if (tid < 64) hbin[tid] = hist16[sh_chunk * 64 + tid];
  __syncthreads();
  if (tid == 0) {
    int cum = sh_above;            // count strictly above chunk's top bin range
    int b = 63;
    for (;; b--) {
      int h = (int)hbin[b];
      if (cum + h >= MAXK || b == 0) { sh_T16 = (unsigned)(sh_chunk * 64 + b); sh_remk = MAXK - cum; break; }
      cum += h;
    }
  }
  __syncthreads();
  const unsigned T16 = sh_T16;
  int remk = sh_remk;

  // ---- collect ----
  if (tid == 0) { cnt_gt = 0; cnt_eq = 0; }
  __syncthreads();
  for (int e = tid; e < NBAND; e += 1024) {
    unsigned key = f2key(band[e]);
    unsigned k16 = key >> 16;
    if (k16 >= T16) {
      int i = e / MAXSPAN, d = e - i * MAXSPAN;
      int fi = i * S + i + d;
      if (k16 > T16) {
        int p = atomicAdd(&cnt_gt, 1);
        if (p < 1024) idxbuf[p] = fi;
      } else {
        int p = atomicAdd(&cnt_eq, 1);
        if (p < 256) { tkey[p] = key; tidx[p] = fi; }
      }
    }
  }
  __syncthreads();

  // ---- parallel bitonic sort of the tie set (desc key, ties asc idx) ----
  for (int ksz2 = 2; ksz2 <= 256; ksz2 <<= 1) {
    for (int jj = ksz2 >> 1; jj > 0; jj >>= 1) {
      if (tid < 256) {
        int ixj = tid ^ jj;
        if (ixj > tid) {
          unsigned ka = tkey[tid], kb = tkey[ixj];
          int ia = tidx[tid], ib = tidx[ixj];
          bool aFirst = (ka > kb) || (ka == kb && ia < ib);
          bool up = ((tid & ksz2) == 0);
          if (up ? !aFirst : aFirst) {
            tkey[tid] = kb; tidx[tid] = ib;
            tkey[ixj] = ka; tidx[ixj] = ia;
          }
        }
      }
      __syncthreads();
    }
  }
  {
    int ngt = cnt_gt < 1024 ? cnt_gt : 1024;
    int ne = cnt_eq < 256 ? cnt_eq : 256;
    int take = remk < ne ? remk : ne;
    if (tid < take && ngt + tid < 1024) idxbuf[ngt + tid] = tidx[tid];
  }
  __syncthreads();

  // ---- bitonic sort of the MAXK indices (ascending) ----
  sb[tid] = (tid < MAXK) ? idxbuf[tid] : 0x7FFFFFFF;
  __syncthreads();
  for (int ksz = 2; ksz <= 1024; ksz <<= 1) {
    for (int jj = ksz >> 1; jj > 0; jj >>= 1) {
      int ixj = tid ^ jj;
      if (ixj > tid) {
        int a2 = sb[tid], b2 = sb[ixj];
        bool up = ((tid & ksz) == 0);
        if (up ? (a2 > b2) : (a2 < b2)) { sb[tid] = b2; sb[ixj] = a2; }
      }
      __syncthreads();
    }
  }
  if (tid < MAXK) {
    int fi = sb[tid];
    out[O_START + tid] = (float)(fi >> 12);
    out[O_END + tid]   = (float)(fi & 4095);
    out[O_MASK + tid]  = 1.0f;
  }

  // ---- cost finalize ----
  if (tid < G) {
    int gs = gold[2 * tid], ge = gold[2 * tid + 1];
    gcell[tid] = gs * MAXSPAN + (ge - gs);
  }
  __syncthreads();
  float tg = 0.0f, tj = 0.0f;
  if (tid < G) {
    int cell = gcell[tid];
    float x = band[cell];
    float p = 1.0f / (1.0f + expf(-x));
    tg = fmaxf(logf(p), -100.0f);
    bool first = true;
    for (int q = 0; q < tid; q++)
      if (gcell[q] == cell) { first = false; break; }
    if (first) tj = fmaxf(logf(1.0f - p), -100.0f);
  }
  float sg = block_reduce_1024(tg, redf);
  float sj = block_reduce_1024(tj, redf);
  if (tid == 0) {
    double junk = *jacc - (double)sj;   // exclude gold cells (set to 0 in reference)
    double cost = -((double)sg / (double)G) - (junk / BAND_COUNT);
    out[O_COST] = (float)cost;
  }
}

// ---------------- launch ----------------

extern "C" void kernel_launch(void* const* d_in, const int* in_sizes, int n_in,
                              void* d_out, int out_size, void* d_ws, size_t ws_size,
                              hipStream_t stream) {
  (void)in_sizes; (void)n_in; (void)out_size; (void)ws_size;
  const float* seq    = (const float*)d_in[0];
  const int*   gold   = (const int*)d_in[2];
  const float* W_sm   = (const float*)d_in[3];
  const float* b_sm   = (const float*)d_in[4];
  const float* g_sm   = (const float*)d_in[5];
  const float* be_sm  = (const float*)d_in[6];
  const float* W_em   = (const float*)d_in[7];
  const float* b_em   = (const float*)d_in[8];
  const float* g_em   = (const float*)d_in[9];
  const float* be_em  = (const float*)d_in[10];
  const float* w_st   = (const float*)d_in[11];
  const float* b_st   = (const float*)d_in[12];
  const float* w_en   = (const float*)d_in[13];
  const float* b_en   = (const float*)d_in[14];
  const float* W_s2e  = (const float*)d_in[15];
  const float* b_s2e  = (const float*)d_in[16];
  float* out = (float*)d_out;
  char* ws = (char*)d_ws;

  const size_t SZ_REP = (size_t)S * FF * 4;          // 50331648
  float*  bufS = (float*)(ws);                       // h_start f32 (gelu out, pre-LN)
  float*  bufE = (float*)(ws + SZ_REP);              // h_end f32 (gelu out, pre-LN)
  float*  bufT = (float*)(ws + 2 * SZ_REP);          // temp f32
  // R3: seq hi/lo tiled during GEMM1/2; reused as a3 (normalized start) hi/lo tiled
  char* R3 = ws + 3 * SZ_REP;
  unsigned short* seqhi = (unsigned short*)R3;
  unsigned short* seqlo = (unsigned short*)(R3 + (size_t)S * H * 2);
  unsigned short* a3hi  = (unsigned short*)R3;
  unsigned short* a3lo  = (unsigned short*)(R3 + (size_t)S * FF * 2);
  // R4: tiled weights. Phase 1: wb1/wb2 (H x FF). Phase 2: wb (FF x FF).
  char* R4 = ws + 4 * SZ_REP;
  const size_t SZ_W12 = (size_t)H * FF * 2;          // 6291456
  unsigned short* wb1hi = (unsigned short*)R4;
  unsigned short* wb1lo = (unsigned short*)(R4 + SZ_W12);
  unsigned short* wb2hi = (unsigned short*)(R4 + 2 * SZ_W12);
  unsigned short* wb2lo = (unsigned short*)(R4 + 3 * SZ_W12);
  unsigned short* wbhi = (unsigned short*)R4;
  unsigned short* wblo = (unsigned short*)(R4 + (size_t)FF * FF * 2);
  // R5: small buffers
  char* R5 = R4 + 2 * (size_t)FF * FF * 2;
  float*    band   = (float*)R5;                              // NBAND f32
  unsigned* hist16 = (unsigned*)(R5 + (size_t)NBAND * 4);     // 65536 bins
  double*   jacc   = (double*)(R5 + (size_t)NBAND * 4 + 262144);
  float*    slog   = (float*)(R5 + (size_t)NBAND * 4 + 262144 + 64);
  float*  elog  = slog + S;
  float*  muS   = elog + S;
  float*  rstdS = muS + S;
  float*  muE   = rstdS + S;
  float*  rstdE = muE + S;

  // zero hist16 + jacc in one memset (jacc sits right after hist16)
  hipMemsetAsync(hist16, 0, 262144 + 64 + 8, stream);

  dim3 gg(16, 16);           // GEMM3: (FF/192, S/256)
  dim3 gg2(16, 16, 2);       // fused GEMM1+2

  // head pack: seq (tiled hi/lo + passthrough copy to out) + both H x FF weights
  pack_head_kernel<<<dim3(32, 320), 256, 0, stream>>>(seq, out + O_SEQ, seqhi, seqlo,
                                                      W_sm, W_em, wb1hi, wb1lo, wb2hi, wb2lo);
  // fused GEMM1+2 (gelu epilogue, 4-wave fat-tile pipeline)
  gemm_mfma_dual_kernel<<<gg2, 256, 0, stream>>>(seqhi, seqlo, wb1hi, wb1lo, wb2hi, wb2lo,
                                                 b_sm, b_em, bufS, bufE, FF, H);
  // LN stats + logits for both branches + fused LN-A pack (start branch)
  ln_stats_kernel<<<dim3(S, 2), 256, 0, stream>>>(bufS, bufE, g_sm, be_sm, w_st, b_st,
                                                  g_em, be_em, w_en, b_en,
                                                  slog, elog, muS, rstdS, muE, rstdE,
                                                  a3hi, a3lo);
  // mid pack: W_s2e only (LN-A pack moved into ln_stats)
  pack_mid_kernel<<<dim3(96, 96), 256, 0, stream>>>(W_s2e, wbhi, wblo);
  // GEMM3 (4-wave fat-tile pipeline)
  gemm_mfma_kernel<<<gg, 256, 0, stream>>>(a3hi, a3lo, wbhi, wblo, b_s2e, bufT, FF, FF);

  // band joint with inline E-LayerNorm + fused junk-cost + 16-bit key histogram
  band_joint_kernel<<<S / 16, 256, 0, stream>>>(bufT, bufE, muE, rstdE, g_em, be_em,
                                                slog, elog, band, jacc, hist16);

  // top-k (threshold from hist) + cost finalize
  topk_finalize_kernel<<<1, 1024, 0, stream>>>(band, gold, jacc, hist16, out);
}

// Round 9
// 748.419 us; speedup vs baseline: 1.3158x; 1.3158x over previous
//
#include <hip/hip_runtime.h>
#include <math.h>

#define S 4096
#define H 1024
#define FF 3072
#define G 100
#define MAXSPAN 30
#define MAXK 819
#define NBAND (S * MAXSPAN)   // 122880 slots, 122445 valid
#define BAND_COUNT 122445.0

// out layout (float32)
#define O_START 0
#define O_END   819
#define O_MASK  1638
#define O_SEQ   2457
#define O_COST  (2457 + S * H)   // 4196761

typedef __bf16 bf16x8 __attribute__((ext_vector_type(8)));
typedef float f32x16 __attribute__((ext_vector_type(16)));

// ---------------- helpers ----------------

__device__ __forceinline__ float block_reduce_256(float x, volatile float* red) {
  #pragma unroll
  for (int off = 32; off > 0; off >>= 1) x += __shfl_down(x, off, 64);
  int wid = threadIdx.x >> 6;
  int lane = threadIdx.x & 63;
  __syncthreads();
  if (lane == 0) red[wid] = x;
  __syncthreads();
  return red[0] + red[1] + red[2] + red[3];
}

__device__ __forceinline__ float block_reduce_1024(float x, volatile float* red) {
  #pragma unroll
  for (int off = 32; off > 0; off >>= 1) x += __shfl_down(x, off, 64);
  int wid = threadIdx.x >> 6;   // 0..15
  int lane = threadIdx.x & 63;
  __syncthreads();
  if (lane == 0) red[wid] = x;
  __syncthreads();
  float s = 0.f;
  #pragma unroll
  for (int q = 0; q < 16; q++) s += red[q];
  return s;
}

__device__ __forceinline__ unsigned f2key(float f) {
  unsigned b = __float_as_uint(f);
  return (b & 0x80000000u) ? ~b : (b | 0x80000000u);
}

__device__ __forceinline__ unsigned short bf16_rne(float x) {
  unsigned u = __float_as_uint(x);
  unsigned r = ((u >> 16) & 1u) + 0x7FFFu;
  return (unsigned short)((u + r) >> 16);
}

__device__ __forceinline__ void split2(float x, unsigned short& h, unsigned short& l) {
  h = bf16_rne(x);
  float hf = __uint_as_float(((unsigned)h) << 16);
  l = bf16_rne(x - hf);
}

__device__ __forceinline__ void gld16(const void* g, void* l) {
  __builtin_amdgcn_global_load_lds(
      (const __attribute__((address_space(1))) unsigned int*)g,
      (__attribute__((address_space(3))) unsigned int*)l, 16, 0, 0);
}

// ---------------- pack bodies: f32 -> hi/lo bf16, tiled [panel][kq][r][8] ----------------
// tiled element offset = panel*(128*K) + kq*1024 + r*8 + s   (panel = row/128, kq = k/8)

__device__ __forceinline__ void pack_a_body(const float* __restrict__ A,
                                            float* __restrict__ Aout,   // optional passthrough copy
                                            unsigned short* __restrict__ hi,
                                            unsigned short* __restrict__ lo,
                                            int K, int bx, int by) {
  __shared__ float tile[32][33];
  const int t = threadIdx.x;
  const int tx = t & 31, ty8 = t >> 5;
  const int k0 = bx * 32, r0 = by * 32;
  #pragma unroll
  for (int r = ty8; r < 32; r += 8) {
    float v = A[(size_t)(r0 + r) * K + k0 + tx];
    tile[r][tx] = v;
    if (Aout) Aout[(size_t)(r0 + r) * K + k0 + tx] = v;
  }
  __syncthreads();
  if (t < 128) {
    const int kql = t >> 5;
    const int rl = t & 31;
    unsigned short h8[8], l8[8];
    #pragma unroll
    for (int s = 0; s < 8; s++) split2(tile[rl][kql * 8 + s], h8[s], l8[s]);
    const size_t panel = (size_t)(r0 >> 7);
    const int rloc = (r0 & 127) + rl;
    const size_t off = panel * (size_t)(128 * K) + (size_t)(k0 / 8 + kql) * 1024 + (size_t)rloc * 8;
    *(uint4*)(hi + off) = *(const uint4*)h8;
    *(uint4*)(lo + off) = *(const uint4*)l8;
  }
}

__device__ __forceinline__ void pack_bt_body(const float* __restrict__ W,
                                             unsigned short* __restrict__ hi,
                                             unsigned short* __restrict__ lo,
                                             int K, int N, int bx, int by) {
  __shared__ float tile[32][33];   // tile[k_local][n_local]
  const int t = threadIdx.x;
  const int tx = t & 31, ty8 = t >> 5;
  const int k0 = bx * 32, n0 = by * 32;
  #pragma unroll
  for (int r = ty8; r < 32; r += 8)
    tile[r][tx] = W[(size_t)(k0 + r) * N + n0 + tx];
  __syncthreads();
  if (t < 128) {
    const int kql = t >> 5;
    const int nl = t & 31;
    unsigned short h8[8], l8[8];
    #pragma unroll
    for (int s = 0; s < 8; s++) split2(tile[kql * 8 + s][nl], h8[s], l8[s]);
    const size_t panel = (size_t)(n0 >> 7);
    const int nloc = (n0 & 127) + nl;
    const size_t off = panel * (size_t)(128 * K) + (size_t)(k0 / 8 + kql) * 1024 + (size_t)nloc * 8;
    *(uint4*)(hi + off) = *(const uint4*)h8;
    *(uint4*)(lo + off) = *(const uint4*)l8;
  }
}

// head pack: seq (+passthrough to out) and both H x FF weights in one dispatch.
// grid (32, 320): y<128 -> pack_a(seq); y<224 -> W_sm; else W_em
__global__ __launch_bounds__(256) void pack_head_kernel(const float* __restrict__ seq,
                                                        float* __restrict__ seq_out,
                                                        unsigned short* __restrict__ sh,
                                                        unsigned short* __restrict__ sl,
                                                        const float* __restrict__ W1,
                                                        const float* __restrict__ W2,
                                                        unsigned short* __restrict__ w1h,
                                                        unsigned short* __restrict__ w1l,
                                                        unsigned short* __restrict__ w2h,
                                                        unsigned short* __restrict__ w2l) {
  const int y = blockIdx.y;
  if (y < 128)      pack_a_body(seq, seq_out, sh, sl, H, blockIdx.x, y);
  else if (y < 224) pack_bt_body(W1, w1h, w1l, H, FF, blockIdx.x, y - 128);
  else              pack_bt_body(W2, w2h, w2l, H, FF, blockIdx.x, y - 224);
}

// mid pack (W_s2e only — LN-A pack fused into ln_stats). grid (96, 96)
__global__ __launch_bounds__(256) void pack_mid_kernel(const float* __restrict__ Ws2e,
                                                       unsigned short* __restrict__ wbh,
                                                       unsigned short* __restrict__ wbl) {
  pack_bt_body(Ws2e, wbh, wbl, FF, FF, blockIdx.x, blockIdx.y);
}

// ---------------- MFMA GEMM core v9 (revert to proven 8-wave config) ----------------
// R8 post-mortem: the 4-wave fat-tile core (v7) spilled (VGPR 208 < 263 needed) and
// collapsed the dual kernel to 328us / MfmaUtil 20% (K=1024: short NH, 2 rounds,
// 1 wave/SIMD = no TLP to hide spill+latency). GEMM3 masked this (K=3072 amortizes).
// v9 = R1/R5 8-wave config: 256x192 tile, 8 waves (512 thr), 2x3 acc/wave (88 VGPR,
// no spill, 2 waves/SIMD), 4 LDS slots, prefetch distance 3, counted vmcnt with the
// CORRECTED tail ladder (R5): end of phase p guarantees slot p+1 complete:
//   p+3<NH -> vmcnt(8); p+2<NH -> vmcnt(4); p+1<NH -> vmcnt(0).
// Single barrier per phase (R5's extra pre-MFMA barrier measured null).
// Per-acc product order hh->lh->hl — bitwise identical output.
//
// LDS slot layout (28672 B): Ah [2kq][256r][8]e = 8192 | Al 8192 | Bh [2kq][192n][8] 6144 | Bl 6144
#define SLOTB 28672
#define A_STR 8192
#define B_BASE 16384
#define B_STR 6144

template <int EPI>
__device__ __forceinline__ void gemm8_body(const char* __restrict__ cAh, const char* __restrict__ cAl,
                                           const char* __restrict__ cBh, const char* __restrict__ cBl,
                                           const float* __restrict__ bias,
                                           float* __restrict__ C,
                                           int bm, int bn, int N, int K,
                                           char* smem) {
  const int tid = threadIdx.x;
  const int lane = tid & 63;
  const int wid = __builtin_amdgcn_readfirstlane(tid >> 6);
  const int wm = wid >> 1, wn = wid & 1;         // 4 x 2 wave grid (64 x 96 per wave)
  const int khalf = lane >> 5;
  const int r31 = lane & 31;
  const size_t PS = (size_t)256 * (size_t)K;     // bytes per 128-row packed panel

  // per-wave stage descriptors: 4 loads each for waves 0..6 (28 loads per 16-k slot)
  const char* lsrc[4];
  int ldst[4];
  #pragma unroll
  for (int i = 0; i < 4; i++) { lsrc[i] = cAh; ldst[i] = 0; }
  if (wid < 7) {
    #pragma unroll
    for (int i = 0; i < 4; i++) {
      int q = wid * 4 + i;
      if (q < 16) {          // A: 2 streams x 2 kq x 4 row-units(64)
        int str = q >> 3, r = q & 7, kql = r >> 2, u = r & 3;
        lsrc[i] = (str ? cAl : cAh) + (size_t)((bm >> 7) + (u >> 1)) * PS
                + (size_t)(kql * 2048 + (u & 1) * 1024 + lane * 16);
        ldst[i] = str * A_STR + kql * 4096 + u * 1024;
      } else {               // B: 2 streams x 2 kq x 3 col-units(64)
        int qq = q - 16;
        int str = qq / 6, r = qq % 6, kql = r / 3, v = r % 3;
        int gcol = bn + 64 * v;
        lsrc[i] = (str ? cBl : cBh) + (size_t)(gcol >> 7) * PS
                + (size_t)(kql * 2048 + ((gcol >> 6) & 1) * 1024 + lane * 16);
        ldst[i] = B_BASE + str * B_STR + kql * 3072 + v * 1024;
      }
    }
  }

  const int aoff = khalf * 4096 + (wm * 64 + r31) * 16;
  const int boff = B_BASE + khalf * 3072 + (wn * 96 + r31) * 16;

  f32x16 acc[2][3];
  #pragma unroll
  for (int mt = 0; mt < 2; mt++)
    #pragma unroll
    for (int nt = 0; nt < 3; nt++)
      #pragma unroll
      for (int r = 0; r < 16; r++) acc[mt][nt][r] = 0.0f;

  auto stage = [&](int h) {
    if (wid < 7) {
      char* sb = smem + (h & 3) * SLOTB;
      const size_t ko = (size_t)h * 4096;   // 2 kq per slot
      #pragma unroll
      for (int i = 0; i < 4; i++) gld16(lsrc[i] + ko, sb + ldst[i]);
    }
  };

  const int NH = K >> 4;   // phases (16 k each); NH >= 4 for all call sites

  // prologue: slots 0,1,2 staged; slot 0 complete after vmcnt(8) + barrier
  stage(0); stage(1); stage(2);
  asm volatile("s_waitcnt vmcnt(8)" ::: "memory");
  __builtin_amdgcn_s_barrier();

  for (int p = 0; p < NH; ++p) {
    const char* sm = smem + (p & 3) * SLOTB;
    bf16x8 ah[2], al[2], bh[3], bl[3];
    // hh operands first: hh MFMAs start after 5 reads; al/bl drain underneath
    // (compiler counted lgkmcnt — no explicit drain).
    #pragma unroll
    for (int mt = 0; mt < 2; mt++) ah[mt] = *(const bf16x8*)(sm + aoff + mt * 512);
    #pragma unroll
    for (int nt = 0; nt < 3; nt++) bh[nt] = *(const bf16x8*)(sm + boff + nt * 512);
    #pragma unroll
    for (int mt = 0; mt < 2; mt++) al[mt] = *(const bf16x8*)(sm + A_STR + aoff + mt * 512);
    #pragma unroll
    for (int nt = 0; nt < 3; nt++) bl[nt] = *(const bf16x8*)(sm + B_STR + boff + nt * 512);
    if (p + 3 < NH) stage(p + 3);
    __builtin_amdgcn_s_setprio(1);
    // per-acc product order hh -> lh -> hl (bitwise identical across all versions)
    #pragma unroll
    for (int mt = 0; mt < 2; mt++)
      #pragma unroll
      for (int nt = 0; nt < 3; nt++) {
        acc[mt][nt] = __builtin_amdgcn_mfma_f32_32x32x16_bf16(ah[mt], bh[nt], acc[mt][nt], 0, 0, 0);
        acc[mt][nt] = __builtin_amdgcn_mfma_f32_32x32x16_bf16(al[mt], bh[nt], acc[mt][nt], 0, 0, 0);
        acc[mt][nt] = __builtin_amdgcn_mfma_f32_32x32x16_bf16(ah[mt], bl[nt], acc[mt][nt], 0, 0, 0);
      }
    __builtin_amdgcn_s_setprio(0);
    // corrected counted ladder: end of phase p guarantees slot p+1 complete.
    if (p + 3 < NH)      { asm volatile("s_waitcnt vmcnt(8)" ::: "memory"); }
    else if (p + 2 < NH) { asm volatile("s_waitcnt vmcnt(4)" ::: "memory"); }
    else if (p + 1 < NH) { asm volatile("s_waitcnt vmcnt(0)" ::: "memory"); }
    if (p + 1 < NH) __builtin_amdgcn_s_barrier();
  }

  #pragma unroll
  for (int mt = 0; mt < 2; mt++) {
    #pragma unroll
    for (int nt = 0; nt < 3; nt++) {
      const int colg = bn + wn * 96 + nt * 32 + r31;
      const float bb = bias[colg];
      #pragma unroll
      for (int reg = 0; reg < 16; reg++) {
        const int rowl = (reg & 3) + 8 * (reg >> 2) + 4 * khalf;
        const int rowg = bm + wm * 64 + mt * 32 + rowl;
        float v = acc[mt][nt][reg] + bb;
        if (EPI == 1) v = 0.5f * v * (1.0f + erff(v * 0.70710678118654752f));
        C[(size_t)rowg * N + colg] = v;
      }
    }
  }
}

// XCD chunk swizzle for the fixed 16x16 block grid: 8 chunks of 4bx x 8by.
__device__ __forceinline__ void grid_swizzle_16x16(int& bx, int& by) {
  const int lin = blockIdx.y * 16 + blockIdx.x;
  const int X = lin & 7, c = lin >> 3;
  bx = (X & 3) * 4 + (c & 3);
  by = (X >> 2) * 8 + (c >> 2);
}

// GEMM3: single output. grid (16,16), 512 threads
__global__ __launch_bounds__(512) void gemm_mfma_kernel(const unsigned short* __restrict__ Ahi,
                                                        const unsigned short* __restrict__ Alo,
                                                        const unsigned short* __restrict__ Bhi,
                                                        const unsigned short* __restrict__ Blo,
                                                        const float* __restrict__ bias,
                                                        float* __restrict__ C,
                                                        int N, int K) {
  __shared__ __align__(16) char smem[4 * SLOTB];
  int bx, by;
  grid_swizzle_16x16(bx, by);
  gemm8_body<0>((const char*)Ahi, (const char*)Alo,
                (const char*)Bhi, (const char*)Blo,
                bias, C, by * 256, bx * 192, N, K, smem);
}

// GEMM1+2 fused: blockIdx.z picks branch (same A), gelu epilogue. grid (16,16,2), 512 threads
__global__ __launch_bounds__(512) void gemm_mfma_dual_kernel(const unsigned short* __restrict__ Ahi,
                                                             const unsigned short* __restrict__ Alo,
                                                             const unsigned short* __restrict__ B1hi,
                                                             const unsigned short* __restrict__ B1lo,
                                                             const unsigned short* __restrict__ B2hi,
                                                             const unsigned short* __restrict__ B2lo,
                                                             const float* __restrict__ bias1,
                                                             const float* __restrict__ bias2,
                                                             float* __restrict__ C1,
                                                             float* __restrict__ C2,
                                                             int N, int K) {
  __shared__ __align__(16) char smem[4 * SLOTB];
  const int zb = blockIdx.z;
  const unsigned short* Bhi = zb ? B2hi : B1hi;
  const unsigned short* Blo = zb ? B2lo : B1lo;
  const float* bias = zb ? bias2 : bias1;
  float* C = zb ? C2 : C1;
  int bx, by;
  grid_swizzle_16x16(bx, by);
  gemm8_body<1>((const char*)Ahi, (const char*)Alo,
                (const char*)Bhi, (const char*)Blo,
                bias, C, by * 256, bx * 192, N, K, smem);
}

// ---------------- LN stats + logit + fused LN-A pack (start branch) ----------------
// grid (S, 2): y=0 start branch (packs a3hi/a3lo), y=1 end branch (stats only).
// The pack writes the SAME bytes the old pack_mid wrote (same split2, same mu/rstd,
// same expression order) — bitwise identical; saves a full 50MB re-read of bufS.

__global__ __launch_bounds__(256) void ln_stats_kernel(const float* __restrict__ HbS,
                                                       const float* __restrict__ HbE,
                                                       const float* __restrict__ gS,
                                                       const float* __restrict__ betaS,
                                                       const float* __restrict__ wS,
                                                       const float* __restrict__ bS,
                                                       const float* __restrict__ gE,
                                                       const float* __restrict__ betaE,
                                                       const float* __restrict__ wE,
                                                       const float* __restrict__ bE,
                                                       float* __restrict__ slog,
                                                       float* __restrict__ elog,
                                                       float* __restrict__ muS,
                                                       float* __restrict__ rstdS,
                                                       float* __restrict__ muE,
                                                       float* __restrict__ rstdE,
                                                       unsigned short* __restrict__ a3hi,
                                                       unsigned short* __restrict__ a3lo) {
  __shared__ float red[4];
  const int row = blockIdx.x, tid = threadIdx.x;
  const int br = blockIdx.y;
  const float* Hb = br ? HbE : HbS;
  const float* g = br ? gE : gS;
  const float* beta = br ? betaE : betaS;
  const float* w = br ? wE : wS;
  const float* bsc = br ? bE : bS;
  const float* h = Hb + (size_t)row * FF;

  float4 v[3];
  float s = 0.0f;
  #pragma unroll
  for (int t = 0; t < 3; t++) {
    v[t] = *(const float4*)(h + tid * 4 + t * 1024);
    s += v[t].x + v[t].y + v[t].z + v[t].w;
  }
  float mu = block_reduce_256(s, red) * (1.0f / (float)FF);

  float s2 = 0.0f;
  #pragma unroll
  for (int t = 0; t < 3; t++) {
    float dx = v[t].x - mu, dy = v[t].y - mu, dz = v[t].z - mu, dw = v[t].w - mu;
    s2 += dx * dx + dy * dy + dz * dz + dw * dw;
  }
  float var = block_reduce_256(s2, red) * (1.0f / (float)FF);
  float rstd = rsqrtf(var + 1e-5f);

  float4 nv[3];
  float dot = 0.0f;
  #pragma unroll
  for (int t = 0; t < 3; t++) {
    int idx = tid * 4 + t * 1024;
    float4 gv = *(const float4*)(g + idx);
    float4 bv = *(const float4*)(beta + idx);
    float4 wv = *(const float4*)(w + idx);
    float rx = (v[t].x - mu) * rstd * gv.x + bv.x;
    float ry = (v[t].y - mu) * rstd * gv.y + bv.y;
    float rz = (v[t].z - mu) * rstd * gv.z + bv.z;
    float rw = (v[t].w - mu) * rstd * gv.w + bv.w;
    nv[t] = make_float4(rx, ry, rz, rw);
    dot += rx * wv.x + ry * wv.y + rz * wv.z + rw * wv.w;
  }
  float dt = block_reduce_256(dot, red);
  if (tid == 0) {
    if (br) { elog[row] = dt + bsc[0]; muE[row] = mu; rstdE[row] = rstd; }
    else    { slog[row] = dt + bsc[0]; muS[row] = mu; rstdS[row] = rstd; }
  }

  if (br == 0) {
    // fused LN-A pack: thread pair (2m, 2m+1) holds cols 8m..8m+7 of each 1024-block
    const size_t panel = (size_t)(row >> 7);
    const int rloc = row & 127;
    #pragma unroll
    for (int t = 0; t < 3; t++) {
      float o0 = __shfl_xor(nv[t].x, 1, 64);
      float o1 = __shfl_xor(nv[t].y, 1, 64);
      float o2 = __shfl_xor(nv[t].z, 1, 64);
      float o3 = __shfl_xor(nv[t].w, 1, 64);
      if ((tid & 1) == 0) {
        float f8[8] = {nv[t].x, nv[t].y, nv[t].z, nv[t].w, o0, o1, o2, o3};
        unsigned short h8[8], l8[8];
        #pragma unroll
        for (int q = 0; q < 8; q++) split2(f8[q], h8[q], l8[q]);
        const int kq = t * 128 + (tid >> 1);
        const size_t off = panel * (size_t)(128 * FF) + (size_t)kq * 1024 + (size_t)rloc * 8;
        *(uint4*)(a3hi + off) = *(const uint4*)h8;
        *(uint4*)(a3lo + off) = *(const uint4*)l8;
      }
    }
  }
}

// ---------------- band joint (inline E-LayerNorm, fused junk sum + 16-bit key histogram) ----------------

__global__ __launch_bounds__(256) void band_joint_kernel(const float* __restrict__ T,
                                                         const float* __restrict__ Eraw,
                                                         const float* __restrict__ muE,
                                                         const float* __restrict__ rstdE,
                                                         const float* __restrict__ gE,
                                                         const float* __restrict__ betaE,
                                                         const float* __restrict__ sl,
                                                         const float* __restrict__ el,
                                                         float* __restrict__ band,
                                                         double* __restrict__ jacc,
                                                         unsigned* __restrict__ hist16) {
  __shared__ float Elds[45][260];   // 260 = 256 + 4 pad
  __shared__ float red[4];
  const int t = threadIdx.x;
  const int bx = blockIdx.x;
  const int sbx = (bx & 7) * 32 + (bx >> 3);   // XCD-locality swizzle (perf heuristic)
  const int i0 = sbx * 16;
  const int r_l = t >> 4, c = t & 15;

  float accd[MAXSPAN];
  #pragma unroll
  for (int d = 0; d < MAXSPAN; d++) accd[d] = 0.0f;

  for (int k0 = 0; k0 < FF; k0 += 256) {
    const float* trow = T + (size_t)(i0 + r_l) * FF + k0 + c * 16;
    float4 tv0 = *(const float4*)(trow + 0);
    float4 tv1 = *(const float4*)(trow + 4);
    float4 tv2 = *(const float4*)(trow + 8);
    float4 tv3 = *(const float4*)(trow + 12);
    __syncthreads();
    for (int rr = t >> 6; rr < 45; rr += 4) {
      int gr = i0 + rr;
      int cc = (t & 63) * 4;
      float4 rv = {0.f, 0.f, 0.f, 0.f};
      if (gr < S) {
        float4 ev = *(const float4*)(Eraw + (size_t)gr * FF + k0 + cc);
        float m = muE[gr], rs = rstdE[gr];
        float4 gv = *(const float4*)(gE + k0 + cc);
        float4 bv = *(const float4*)(betaE + k0 + cc);
        rv.x = (ev.x - m) * rs * gv.x + bv.x;
        rv.y = (ev.y - m) * rs * gv.y + bv.y;
        rv.z = (ev.z - m) * rs * gv.z + bv.z;
        rv.w = (ev.w - m) * rs * gv.w + bv.w;
      }
      *(float4*)&Elds[rr][cc] = rv;
    }
    __syncthreads();
    #pragma unroll
    for (int d = 0; d < MAXSPAN; d++) {
      const float* er = &Elds[r_l + d][c * 16];
      float4 e0 = *(const float4*)(er + 0);
      float4 e1 = *(const float4*)(er + 4);
      float4 e2 = *(const float4*)(er + 8);
      float4 e3 = *(const float4*)(er + 12);
      accd[d] += tv0.x * e0.x + tv0.y * e0.y + tv0.z * e0.z + tv0.w * e0.w
               + tv1.x * e1.x + tv1.y * e1.y + tv1.z * e1.z + tv1.w * e1.w
               + tv2.x * e2.x + tv2.y * e2.y + tv2.z * e2.z + tv2.w * e2.w
               + tv3.x * e3.x + tv3.y * e3.y + tv3.z * e3.z + tv3.w * e3.w;
    }
  }

  const int i = i0 + r_l;
  const float my_sl = sl[i];
  float jsum = 0.0f;
  #pragma unroll
  for (int d = 0; d < MAXSPAN; d++) {
    float v = accd[d];
    v += __shfl_down(v, 8, 16);
    v += __shfl_down(v, 4, 16);
    v += __shfl_down(v, 2, 16);
    v += __shfl_down(v, 1, 16);
    if (c == 0) {
      int j = i + d;
      if (j < S) {
        float vv = v + my_sl + el[j];
        vv = fminf(fmaxf(vv, -10000.0f), 10000.0f);
        band[i * MAXSPAN + d] = vv;
        atomicAdd(&hist16[f2key(vv) >> 16], 1u);
        float p = 1.0f / (1.0f + expf(-vv));
        jsum += fmaxf(logf(1.0f - p), -100.0f);
      } else {
        band[i * MAXSPAN + d] = -1e30f;
      }
    }
  }
  float tot = block_reduce_256(jsum, red);
  if (t == 0) atomicAdd(jacc, (double)tot);
}

// ---------------- top-k + cost finalize (single block; parallelized) ----------------
// (a) uint4 histogram sum, (b) LDS-staged threshold-bin scan, (c) parallel
// bitonic sort of the threshold-tie set. Selection semantics identical:
// descending full-key, ties ascending index.

__global__ __launch_bounds__(1024) void topk_finalize_kernel(const float* __restrict__ band,
                                                             const int* __restrict__ gold,
                                                             const double* __restrict__ jacc,
                                                             const unsigned* __restrict__ hist16,
                                                             float* __restrict__ out) {
  __shared__ int csum[1024];
  __shared__ unsigned sh_T16;
  __shared__ int sh_remk;
  __shared__ int sh_chunk, sh_above;
  __shared__ unsigned hbin[64];
  __shared__ int idxbuf[1024];
  __shared__ unsigned tkey[256];
  __shared__ int tidx[256];
  __shared__ int cnt_gt, cnt_eq;
  __shared__ int sb[1024];
  __shared__ int gcell[G];
  __shared__ float redf[16];
  const int tid = threadIdx.x;

  // ---- threshold from 65536-bin histogram (vectorized sum) ----
  int s = 0;
  {
    const uint4* hv = (const uint4*)hist16 + (size_t)tid * 16;
    #pragma unroll
    for (int q = 0; q < 16; q++) {
      uint4 u = hv[q];
      s += (int)(u.x + u.y + u.z + u.w);
    }
  }
  csum[tid] = s;
  if (tid < 256) { tkey[tid] = 0u; tidx[tid] = 0x7FFFFFFF; }   // padding for bitonic
  __syncthreads();
  // suffix sum (Hillis-Steele): csum[t] = sum over chunks >= t
  for (int off = 1; off < 1024; off <<= 1) {
    int v = (tid + off < 1024) ? csum[tid + off] : 0;
    __syncthreads();
    csum[tid] += v;
    __syncthreads();
  }
  // csum non-increasing; find chunk containing the rank-MAXK crossing
  {
    int nxt = (tid < 1023) ? csum[tid + 1] : 0;
    if (csum[tid] >= MAXK && nxt < MAXK) { sh_chunk = tid; sh_above = nxt; }
  }
  __syncthreads();
  if (tid < 64) hbin[tid] = hist16[sh_chunk * 64 + tid];
  __syncthreads();
  if (tid == 0) {
    int cum = sh_above;            // count strictly above chunk's top bin range
    int b = 63;
    for (;; b--) {
      int h = (int)hbin[b];
      if (cum + h >= MAXK || b == 0) { sh_T16 = (unsigned)(sh_chunk * 64 + b); sh_remk = MAXK - cum; break; }
      cum += h;
    }
  }
  __syncthreads();
  const unsigned T16 = sh_T16;
  int remk = sh_remk;

  // ---- collect ----
  if (tid == 0) { cnt_gt = 0; cnt_eq = 0; }
  __syncthreads();
  for (int e = tid; e < NBAND; e += 1024) {
    unsigned key = f2key(band[e]);
    unsigned k16 = key >> 16;
    if (k16 >= T16) {
      int i = e / MAXSPAN, d = e - i * MAXSPAN;
      int fi = i * S + i + d;
      if (k16 > T16) {
        int p = atomicAdd(&cnt_gt, 1);
        if (p < 1024) idxbuf[p] = fi;
      } else {
        int p = atomicAdd(&cnt_eq, 1);
        if (p < 256) { tkey[p] = key; tidx[p] = fi; }
      }
    }
  }
  __syncthreads();

  // ---- parallel bitonic sort of the tie set (desc key, ties asc idx) ----
  for (int ksz2 = 2; ksz2 <= 256; ksz2 <<= 1) {
    for (int jj = ksz2 >> 1; jj > 0; jj >>= 1) {
      if (tid < 256) {
        int ixj = tid ^ jj;
        if (ixj > tid) {
          unsigned ka = tkey[tid], kb = tkey[ixj];
          int ia = tidx[tid], ib = tidx[ixj];
          bool aFirst = (ka > kb) || (ka == kb && ia < ib);
          bool up = ((tid & ksz2) == 0);
          if (up ? !aFirst : aFirst) {
            tkey[tid] = kb; tidx[tid] = ib;
            tkey[ixj] = ka; tidx[ixj] = ia;
          }
        }
      }
      __syncthreads();
    }
  }
  {
    int ngt = cnt_gt < 1024 ? cnt_gt : 1024;
    int ne = cnt_eq < 256 ? cnt_eq : 256;
    int take = remk < ne ? remk : ne;
    if (tid < take && ngt + tid < 1024) idxbuf[ngt + tid] = tidx[tid];
  }
  __syncthreads();

  // ---- bitonic sort of the MAXK indices (ascending) ----
  sb[tid] = (tid < MAXK) ? idxbuf[tid] : 0x7FFFFFFF;
  __syncthreads();
  for (int ksz = 2; ksz <= 1024; ksz <<= 1) {
    for (int jj = ksz >> 1; jj > 0; jj >>= 1) {
      int ixj = tid ^ jj;
      if (ixj > tid) {
        int a2 = sb[tid], b2 = sb[ixj];
        bool up = ((tid & ksz) == 0);
        if (up ? (a2 > b2) : (a2 < b2)) { sb[tid] = b2; sb[ixj] = a2; }
      }
      __syncthreads();
    }
  }
  if (tid < MAXK) {
    int fi = sb[tid];
    out[O_START + tid] = (float)(fi >> 12);
    out[O_END + tid]   = (float)(fi & 4095);
    out[O_MASK + tid]  = 1.0f;
  }

  // ---- cost finalize ----
  if (tid < G) {
    int gs = gold[2 * tid], ge = gold[2 * tid + 1];
    gcell[tid] = gs * MAXSPAN + (ge - gs);
  }
  __syncthreads();
  float tg = 0.0f, tj = 0.0f;
  if (tid < G) {
    int cell = gcell[tid];
    float x = band[cell];
    float p = 1.0f / (1.0f + expf(-x));
    tg = fmaxf(logf(p), -100.0f);
    bool first = true;
    for (int q = 0; q < tid; q++)
      if (gcell[q] == cell) { first = false; break; }
    if (first) tj = fmaxf(logf(1.0f - p), -100.0f);
  }
  float sg = block_reduce_1024(tg, redf);
  float sj = block_reduce_1024(tj, redf);
  if (tid == 0) {
    double junk = *jacc - (double)sj;   // exclude gold cells (set to 0 in reference)
    double cost = -((double)sg / (double)G) - (junk / BAND_COUNT);
    out[O_COST] = (float)cost;
  }
}

// ---------------- launch ----------------

extern "C" void kernel_launch(void* const* d_in, const int* in_sizes, int n_in,
                              void* d_out, int out_size, void* d_ws, size_t ws_size,
                              hipStream_t stream) {
  (void)in_sizes; (void)n_in; (void)out_size; (void)ws_size;
  const float* seq    = (const float*)d_in[0];
  const int*   gold   = (const int*)d_in[2];
  const float* W_sm   = (const float*)d_in[3];
  const float* b_sm   = (const float*)d_in[4];
  const float* g_sm   = (const float*)d_in[5];
  const float* be_sm  = (const float*)d_in[6];
  const float* W_em   = (const float*)d_in[7];
  const float* b_em   = (const float*)d_in[8];
  const float* g_em   = (const float*)d_in[9];
  const float* be_em  = (const float*)d_in[10];
  const float* w_st   = (const float*)d_in[11];
  const float* b_st   = (const float*)d_in[12];
  const float* w_en   = (const float*)d_in[13];
  const float* b_en   = (const float*)d_in[14];
  const float* W_s2e  = (const float*)d_in[15];
  const float* b_s2e  = (const float*)d_in[16];
  float* out = (float*)d_out;
  char* ws = (char*)d_ws;

  const size_t SZ_REP = (size_t)S * FF * 4;          // 50331648
  float*  bufS = (float*)(ws);                       // h_start f32 (gelu out, pre-LN)
  float*  bufE = (float*)(ws + SZ_REP);              // h_end f32 (gelu out, pre-LN)
  float*  bufT = (float*)(ws + 2 * SZ_REP);          // temp f32
  // R3: seq hi/lo tiled during GEMM1/2; reused as a3 (normalized start) hi/lo tiled
  char* R3 = ws + 3 * SZ_REP;
  unsigned short* seqhi = (unsigned short*)R3;
  unsigned short* seqlo = (unsigned short*)(R3 + (size_t)S * H * 2);
  unsigned short* a3hi  = (unsigned short*)R3;
  unsigned short* a3lo  = (unsigned short*)(R3 + (size_t)S * FF * 2);
  // R4: tiled weights. Phase 1: wb1/wb2 (H x FF). Phase 2: wb (FF x FF).
  char* R4 = ws + 4 * SZ_REP;
  const size_t SZ_W12 = (size_t)H * FF * 2;          // 6291456
  unsigned short* wb1hi = (unsigned short*)R4;
  unsigned short* wb1lo = (unsigned short*)(R4 + SZ_W12);
  unsigned short* wb2hi = (unsigned short*)(R4 + 2 * SZ_W12);
  unsigned short* wb2lo = (unsigned short*)(R4 + 3 * SZ_W12);
  unsigned short* wbhi = (unsigned short*)R4;
  unsigned short* wblo = (unsigned short*)(R4 + (size_t)FF * FF * 2);
  // R5: small buffers
  char* R5 = R4 + 2 * (size_t)FF * FF * 2;
  float*    band   = (float*)R5;                              // NBAND f32
  unsigned* hist16 = (unsigned*)(R5 + (size_t)NBAND * 4);     // 65536 bins
  double*   jacc   = (double*)(R5 + (size_t)NBAND * 4 + 262144);
  float*    slog   = (float*)(R5 + (size_t)NBAND * 4 + 262144 + 64);
  float*  elog  = slog + S;
  float*  muS   = elog + S;
  float*  rstdS = muS + S;
  float*  muE   = rstdS + S;
  float*  rstdE = muE + S;

  // zero hist16 + jacc in one memset (jacc sits right after hist16)
  hipMemsetAsync(hist16, 0, 262144 + 64 + 8, stream);

  dim3 gg(16, 16);           // GEMM3: (FF/192, S/256)
  dim3 gg2(16, 16, 2);       // fused GEMM1+2

  // head pack: seq (tiled hi/lo + passthrough copy to out) + both H x FF weights
  pack_head_kernel<<<dim3(32, 320), 256, 0, stream>>>(seq, out + O_SEQ, seqhi, seqlo,
                                                      W_sm, W_em, wb1hi, wb1lo, wb2hi, wb2lo);
  // fused GEMM1+2 (gelu epilogue, 8-wave pipeline)
  gemm_mfma_dual_kernel<<<gg2, 512, 0, stream>>>(seqhi, seqlo, wb1hi, wb1lo, wb2hi, wb2lo,
                                                 b_sm, b_em, bufS, bufE, FF, H);
  // LN stats + logits for both branches + fused LN-A pack (start branch)
  ln_stats_kernel<<<dim3(S, 2), 256, 0, stream>>>(bufS, bufE, g_sm, be_sm, w_st, b_st,
                                                  g_em, be_em, w_en, b_en,
                                                  slog, elog, muS, rstdS, muE, rstdE,
                                                  a3hi, a3lo);
  // mid pack: W_s2e only (LN-A pack moved into ln_stats)
  pack_mid_kernel<<<dim3(96, 96), 256, 0, stream>>>(W_s2e, wbhi, wblo);
  // GEMM3 (8-wave pipeline)
  gemm_mfma_kernel<<<gg, 512, 0, stream>>>(a3hi, a3lo, wbhi, wblo, b_s2e, bufT, FF, FF);

  // band joint with inline E-LayerNorm + fused junk-cost + 16-bit key histogram
  band_joint_kernel<<<S / 16, 256, 0, stream>>>(bufT, bufE, muE, rstdE, g_em, be_em,
                                                slog, elog, band, jacc, hist16);

  // top-k (threshold from hist) + cost finalize
  topk_finalize_kernel<<<1, 1024, 0, stream>>>(band, gold, jacc, hist16, out);
}

// Round 10
// 741.735 us; speedup vs baseline: 1.3277x; 1.0090x over previous
//
#include <hip/hip_runtime.h>
#include <math.h>

#define S 4096
#define H 1024
#define FF 3072
#define G 100
#define MAXSPAN 30
#define MAXK 819
#define NBAND (S * MAXSPAN)   // 122880 slots, 122445 valid
#define BAND_COUNT 122445.0

// out layout (float32)
#define O_START 0
#define O_END   819
#define O_MASK  1638
#define O_SEQ   2457
#define O_COST  (2457 + S * H)   // 4196761

typedef __bf16 bf16x8 __attribute__((ext_vector_type(8)));
typedef float f32x16 __attribute__((ext_vector_type(16)));

// ---------------- helpers ----------------

__device__ __forceinline__ float block_reduce_256(float x, volatile float* red) {
  #pragma unroll
  for (int off = 32; off > 0; off >>= 1) x += __shfl_down(x, off, 64);
  int wid = threadIdx.x >> 6;
  int lane = threadIdx.x & 63;
  __syncthreads();
  if (lane == 0) red[wid] = x;
  __syncthreads();
  return red[0] + red[1] + red[2] + red[3];
}

__device__ __forceinline__ float block_reduce_1024(float x, volatile float* red) {
  #pragma unroll
  for (int off = 32; off > 0; off >>= 1) x += __shfl_down(x, off, 64);
  int wid = threadIdx.x >> 6;   // 0..15
  int lane = threadIdx.x & 63;
  __syncthreads();
  if (lane == 0) red[wid] = x;
  __syncthreads();
  float s = 0.f;
  #pragma unroll
  for (int q = 0; q < 16; q++) s += red[q];
  return s;
}

__device__ __forceinline__ unsigned f2key(float f) {
  unsigned b = __float_as_uint(f);
  return (b & 0x80000000u) ? ~b : (b | 0x80000000u);
}

__device__ __forceinline__ unsigned short bf16_rne(float x) {
  unsigned u = __float_as_uint(x);
  unsigned r = ((u >> 16) & 1u) + 0x7FFFu;
  return (unsigned short)((u + r) >> 16);
}

__device__ __forceinline__ void split2(float x, unsigned short& h, unsigned short& l) {
  h = bf16_rne(x);
  float hf = __uint_as_float(((unsigned)h) << 16);
  l = bf16_rne(x - hf);
}

__device__ __forceinline__ void gld16(const void* g, void* l) {
  __builtin_amdgcn_global_load_lds(
      (const __attribute__((address_space(1))) unsigned int*)g,
      (__attribute__((address_space(3))) unsigned int*)l, 16, 0, 0);
}

// ---------------- pack bodies: f32 -> hi/lo bf16, tiled [panel][kq][r][8] ----------------
// tiled element offset = panel*(128*K) + kq*1024 + r*8 + s   (panel = row/128, kq = k/8)

__device__ __forceinline__ void pack_a_body(const float* __restrict__ A,
                                            float* __restrict__ Aout,   // optional passthrough copy
                                            unsigned short* __restrict__ hi,
                                            unsigned short* __restrict__ lo,
                                            int K, int bx, int by) {
  __shared__ float tile[32][33];
  const int t = threadIdx.x;
  const int tx = t & 31, ty8 = t >> 5;
  const int k0 = bx * 32, r0 = by * 32;
  #pragma unroll
  for (int r = ty8; r < 32; r += 8) {
    float v = A[(size_t)(r0 + r) * K + k0 + tx];
    tile[r][tx] = v;
    if (Aout) Aout[(size_t)(r0 + r) * K + k0 + tx] = v;
  }
  __syncthreads();
  if (t < 128) {
    const int kql = t >> 5;
    const int rl = t & 31;
    unsigned short h8[8], l8[8];
    #pragma unroll
    for (int s = 0; s < 8; s++) split2(tile[rl][kql * 8 + s], h8[s], l8[s]);
    const size_t panel = (size_t)(r0 >> 7);
    const int rloc = (r0 & 127) + rl;
    const size_t off = panel * (size_t)(128 * K) + (size_t)(k0 / 8 + kql) * 1024 + (size_t)rloc * 8;
    *(uint4*)(hi + off) = *(const uint4*)h8;
    *(uint4*)(lo + off) = *(const uint4*)l8;
  }
}

__device__ __forceinline__ void pack_ln_a_body(const float* __restrict__ A,
                                               const float* __restrict__ mu,
                                               const float* __restrict__ rstd,
                                               const float* __restrict__ g,
                                               const float* __restrict__ beta,
                                               unsigned short* __restrict__ hi,
                                               unsigned short* __restrict__ lo,
                                               int K, int bx, int by) {
  __shared__ float tile[32][33];
  const int t = threadIdx.x;
  const int tx = t & 31, ty8 = t >> 5;
  const int k0 = bx * 32, r0 = by * 32;
  #pragma unroll
  for (int r = ty8; r < 32; r += 8)
    tile[r][tx] = A[(size_t)(r0 + r) * K + k0 + tx];
  __syncthreads();
  if (t < 128) {
    const int kql = t >> 5;
    const int rl = t & 31;
    const int row = r0 + rl;
    const float m = mu[row], rs = rstd[row];
    float4 g0 = *(const float4*)(g + k0 + kql * 8);
    float4 g1 = *(const float4*)(g + k0 + kql * 8 + 4);
    float4 b0 = *(const float4*)(beta + k0 + kql * 8);
    float4 b1 = *(const float4*)(beta + k0 + kql * 8 + 4);
    float gv[8] = {g0.x, g0.y, g0.z, g0.w, g1.x, g1.y, g1.z, g1.w};
    float bv[8] = {b0.x, b0.y, b0.z, b0.w, b1.x, b1.y, b1.z, b1.w};
    unsigned short h8[8], l8[8];
    #pragma unroll
    for (int s = 0; s < 8; s++) {
      float v = (tile[rl][kql * 8 + s] - m) * rs * gv[s] + bv[s];
      split2(v, h8[s], l8[s]);
    }
    const size_t panel = (size_t)(r0 >> 7);
    const int rloc = (r0 & 127) + rl;
    const size_t off = panel * (size_t)(128 * K) + (size_t)(k0 / 8 + kql) * 1024 + (size_t)rloc * 8;
    *(uint4*)(hi + off) = *(const uint4*)h8;
    *(uint4*)(lo + off) = *(const uint4*)l8;
  }
}

__device__ __forceinline__ void pack_bt_body(const float* __restrict__ W,
                                             unsigned short* __restrict__ hi,
                                             unsigned short* __restrict__ lo,
                                             int K, int N, int bx, int by) {
  __shared__ float tile[32][33];   // tile[k_local][n_local]
  const int t = threadIdx.x;
  const int tx = t & 31, ty8 = t >> 5;
  const int k0 = bx * 32, n0 = by * 32;
  #pragma unroll
  for (int r = ty8; r < 32; r += 8)
    tile[r][tx] = W[(size_t)(k0 + r) * N + n0 + tx];
  __syncthreads();
  if (t < 128) {
    const int kql = t >> 5;
    const int nl = t & 31;
    unsigned short h8[8], l8[8];
    #pragma unroll
    for (int s = 0; s < 8; s++) split2(tile[kql * 8 + s][nl], h8[s], l8[s]);
    const size_t panel = (size_t)(n0 >> 7);
    const int nloc = (n0 & 127) + nl;
    const size_t off = panel * (size_t)(128 * K) + (size_t)(k0 / 8 + kql) * 1024 + (size_t)nloc * 8;
    *(uint4*)(hi + off) = *(const uint4*)h8;
    *(uint4*)(lo + off) = *(const uint4*)l8;
  }
}

// head pack: seq (+passthrough to out) and both H x FF weights in one dispatch.
// grid (32, 320): y<128 -> pack_a(seq); y<224 -> W_sm; else W_em
__global__ __launch_bounds__(256) void pack_head_kernel(const float* __restrict__ seq,
                                                        float* __restrict__ seq_out,
                                                        unsigned short* __restrict__ sh,
                                                        unsigned short* __restrict__ sl,
                                                        const float* __restrict__ W1,
                                                        const float* __restrict__ W2,
                                                        unsigned short* __restrict__ w1h,
                                                        unsigned short* __restrict__ w1l,
                                                        unsigned short* __restrict__ w2h,
                                                        unsigned short* __restrict__ w2l) {
  const int y = blockIdx.y;
  if (y < 128)      pack_a_body(seq, seq_out, sh, sl, H, blockIdx.x, y);
  else if (y < 224) pack_bt_body(W1, w1h, w1l, H, FF, blockIdx.x, y - 128);
  else              pack_bt_body(W2, w2h, w2l, H, FF, blockIdx.x, y - 224);
}

// mid pack: LN-fused A pack (start branch, coalesced writes) + W_s2e B pack.
// grid (96, 224): y<128 -> pack_ln_a; else pack_bt(W_s2e)
// (R10: reverted the ln_stats-fused pack — it wrote one row across 384 tile
// columns at 2KB stride = scattered 16B stores with cross-XCD sector sharing;
// this tile-shaped pack writes 512B coalesced bursts.)
__global__ __launch_bounds__(256) void pack_mid_kernel(const float* __restrict__ bufS,
                                                       const float* __restrict__ muS,
                                                       const float* __restrict__ rstdS,
                                                       const float* __restrict__ g,
                                                       const float* __restrict__ beta,
                                                       unsigned short* __restrict__ ahi,
                                                       unsigned short* __restrict__ alo,
                                                       const float* __restrict__ Ws2e,
                                                       unsigned short* __restrict__ wbh,
                                                       unsigned short* __restrict__ wbl) {
  const int y = blockIdx.y;
  if (y < 128) pack_ln_a_body(bufS, muS, rstdS, g, beta, ahi, alo, FF, blockIdx.x, y);
  else         pack_bt_body(Ws2e, wbh, wbl, FF, FF, blockIdx.x, y - 128);
}

// ---------------- MFMA GEMM core v9 (proven 8-wave config) ----------------
// 256x192 tile, 8 waves (512 thr), 2x3 acc/wave (88 VGPR, no spill, 2 waves/SIMD),
// 4 LDS slots, prefetch distance 3, counted vmcnt with the corrected tail ladder:
//   p+3<NH -> vmcnt(8); p+2<NH -> vmcnt(4); p+1<NH -> vmcnt(0).
// Single barrier per phase. Per-acc product order hh->lh->hl — bitwise identical.
//
// LDS slot layout (28672 B): Ah [2kq][256r][8]e = 8192 | Al 8192 | Bh [2kq][192n][8] 6144 | Bl 6144
#define SLOTB 28672
#define A_STR 8192
#define B_BASE 16384
#define B_STR 6144

template <int EPI>
__device__ __forceinline__ void gemm8_body(const char* __restrict__ cAh, const char* __restrict__ cAl,
                                           const char* __restrict__ cBh, const char* __restrict__ cBl,
                                           const float* __restrict__ bias,
                                           float* __restrict__ C,
                                           int bm, int bn, int N, int K,
                                           char* smem) {
  const int tid = threadIdx.x;
  const int lane = tid & 63;
  const int wid = __builtin_amdgcn_readfirstlane(tid >> 6);
  const int wm = wid >> 1, wn = wid & 1;         // 4 x 2 wave grid (64 x 96 per wave)
  const int khalf = lane >> 5;
  const int r31 = lane & 31;
  const size_t PS = (size_t)256 * (size_t)K;     // bytes per 128-row packed panel

  // per-wave stage descriptors: 4 loads each for waves 0..6 (28 loads per 16-k slot)
  const char* lsrc[4];
  int ldst[4];
  #pragma unroll
  for (int i = 0; i < 4; i++) { lsrc[i] = cAh; ldst[i] = 0; }
  if (wid < 7) {
    #pragma unroll
    for (int i = 0; i < 4; i++) {
      int q = wid * 4 + i;
      if (q < 16) {          // A: 2 streams x 2 kq x 4 row-units(64)
        int str = q >> 3, r = q & 7, kql = r >> 2, u = r & 3;
        lsrc[i] = (str ? cAl : cAh) + (size_t)((bm >> 7) + (u >> 1)) * PS
                + (size_t)(kql * 2048 + (u & 1) * 1024 + lane * 16);
        ldst[i] = str * A_STR + kql * 4096 + u * 1024;
      } else {               // B: 2 streams x 2 kq x 3 col-units(64)
        int qq = q - 16;
        int str = qq / 6, r = qq % 6, kql = r / 3, v = r % 3;
        int gcol = bn + 64 * v;
        lsrc[i] = (str ? cBl : cBh) + (size_t)(gcol >> 7) * PS
                + (size_t)(kql * 2048 + ((gcol >> 6) & 1) * 1024 + lane * 16);
        ldst[i] = B_BASE + str * B_STR + kql * 3072 + v * 1024;
      }
    }
  }

  const int aoff = khalf * 4096 + (wm * 64 + r31) * 16;
  const int boff = B_BASE + khalf * 3072 + (wn * 96 + r31) * 16;

  f32x16 acc[2][3];
  #pragma unroll
  for (int mt = 0; mt < 2; mt++)
    #pragma unroll
    for (int nt = 0; nt < 3; nt++)
      #pragma unroll
      for (int r = 0; r < 16; r++) acc[mt][nt][r] = 0.0f;

  auto stage = [&](int h) {
    if (wid < 7) {
      char* sb = smem + (h & 3) * SLOTB;
      const size_t ko = (size_t)h * 4096;   // 2 kq per slot
      #pragma unroll
      for (int i = 0; i < 4; i++) gld16(lsrc[i] + ko, sb + ldst[i]);
    }
  };

  const int NH = K >> 4;   // phases (16 k each); NH >= 4 for all call sites

  // prologue: slots 0,1,2 staged; slot 0 complete after vmcnt(8) + barrier
  stage(0); stage(1); stage(2);
  asm volatile("s_waitcnt vmcnt(8)" ::: "memory");
  __builtin_amdgcn_s_barrier();

  for (int p = 0; p < NH; ++p) {
    const char* sm = smem + (p & 3) * SLOTB;
    bf16x8 ah[2], al[2], bh[3], bl[3];
    // hh operands first: hh MFMAs start after 5 reads; al/bl drain underneath
    // (compiler counted lgkmcnt — no explicit drain).
    #pragma unroll
    for (int mt = 0; mt < 2; mt++) ah[mt] = *(const bf16x8*)(sm + aoff + mt * 512);
    #pragma unroll
    for (int nt = 0; nt < 3; nt++) bh[nt] = *(const bf16x8*)(sm + boff + nt * 512);
    #pragma unroll
    for (int mt = 0; mt < 2; mt++) al[mt] = *(const bf16x8*)(sm + A_STR + aoff + mt * 512);
    #pragma unroll
    for (int nt = 0; nt < 3; nt++) bl[nt] = *(const bf16x8*)(sm + B_STR + boff + nt * 512);
    if (p + 3 < NH) stage(p + 3);
    __builtin_amdgcn_s_setprio(1);
    // per-acc product order hh -> lh -> hl (bitwise identical across all versions)
    #pragma unroll
    for (int mt = 0; mt < 2; mt++)
      #pragma unroll
      for (int nt = 0; nt < 3; nt++) {
        acc[mt][nt] = __builtin_amdgcn_mfma_f32_32x32x16_bf16(ah[mt], bh[nt], acc[mt][nt], 0, 0, 0);
        acc[mt][nt] = __builtin_amdgcn_mfma_f32_32x32x16_bf16(al[mt], bh[nt], acc[mt][nt], 0, 0, 0);
        acc[mt][nt] = __builtin_amdgcn_mfma_f32_32x32x16_bf16(ah[mt], bl[nt], acc[mt][nt], 0, 0, 0);
      }
    __builtin_amdgcn_s_setprio(0);
    // corrected counted ladder: end of phase p guarantees slot p+1 complete.
    if (p + 3 < NH)      { asm volatile("s_waitcnt vmcnt(8)" ::: "memory"); }
    else if (p + 2 < NH) { asm volatile("s_waitcnt vmcnt(4)" ::: "memory"); }
    else if (p + 1 < NH) { asm volatile("s_waitcnt vmcnt(0)" ::: "memory"); }
    if (p + 1 < NH) __builtin_amdgcn_s_barrier();
  }

  #pragma unroll
  for (int mt = 0; mt < 2; mt++) {
    #pragma unroll
    for (int nt = 0; nt < 3; nt++) {
      const int colg = bn + wn * 96 + nt * 32 + r31;
      const float bb = bias[colg];
      #pragma unroll
      for (int reg = 0; reg < 16; reg++) {
        const int rowl = (reg & 3) + 8 * (reg >> 2) + 4 * khalf;
        const int rowg = bm + wm * 64 + mt * 32 + rowl;
        float v = acc[mt][nt][reg] + bb;
        if (EPI == 1) v = 0.5f * v * (1.0f + erff(v * 0.70710678118654752f));
        C[(size_t)rowg * N + colg] = v;
      }
    }
  }
}

// XCD chunk swizzle for the fixed 16x16 block grid: 8 chunks of 4bx x 8by.
__device__ __forceinline__ void grid_swizzle_16x16(int& bx, int& by) {
  const int lin = blockIdx.y * 16 + blockIdx.x;
  const int X = lin & 7, c = lin >> 3;
  bx = (X & 3) * 4 + (c & 3);
  by = (X >> 2) * 8 + (c >> 2);
}

// GEMM3: single output. grid (16,16), 512 threads
__global__ __launch_bounds__(512) void gemm_mfma_kernel(const unsigned short* __restrict__ Ahi,
                                                        const unsigned short* __restrict__ Alo,
                                                        const unsigned short* __restrict__ Bhi,
                                                        const unsigned short* __restrict__ Blo,
                                                        const float* __restrict__ bias,
                                                        float* __restrict__ C,
                                                        int N, int K) {
  __shared__ __align__(16) char smem[4 * SLOTB];
  int bx, by;
  grid_swizzle_16x16(bx, by);
  gemm8_body<0>((const char*)Ahi, (const char*)Alo,
                (const char*)Bhi, (const char*)Blo,
                bias, C, by * 256, bx * 192, N, K, smem);
}

// GEMM1+2 fused: blockIdx.z picks branch (same A), gelu epilogue. grid (16,16,2), 512 threads
__global__ __launch_bounds__(512) void gemm_mfma_dual_kernel(const unsigned short* __restrict__ Ahi,
                                                             const unsigned short* __restrict__ Alo,
                                                             const unsigned short* __restrict__ B1hi,
                                                             const unsigned short* __restrict__ B1lo,
                                                             const unsigned short* __restrict__ B2hi,
                                                             const unsigned short* __restrict__ B2lo,
                                                             const float* __restrict__ bias1,
                                                             const float* __restrict__ bias2,
                                                             float* __restrict__ C1,
                                                             float* __restrict__ C2,
                                                             int N, int K) {
  __shared__ __align__(16) char smem[4 * SLOTB];
  const int zb = blockIdx.z;
  const unsigned short* Bhi = zb ? B2hi : B1hi;
  const unsigned short* Blo = zb ? B2lo : B1lo;
  const float* bias = zb ? bias2 : bias1;
  float* C = zb ? C2 : C1;
  int bx, by;
  grid_swizzle_16x16(bx, by);
  gemm8_body<1>((const char*)Ahi, (const char*)Alo,
                (const char*)Bhi, (const char*)Blo,
                bias, C, by * 256, bx * 192, N, K, smem);
}

// ---------------- LN stats + logit (no writeback), both branches ----------------
// grid (S, 2): y=0 start branch, y=1 end branch

__global__ __launch_bounds__(256) void ln_stats_kernel(const float* __restrict__ HbS,
                                                       const float* __restrict__ HbE,
                                                       const float* __restrict__ gS,
                                                       const float* __restrict__ betaS,
                                                       const float* __restrict__ wS,
                                                       const float* __restrict__ bS,
                                                       const float* __restrict__ gE,
                                                       const float* __restrict__ betaE,
                                                       const float* __restrict__ wE,
                                                       const float* __restrict__ bE,
                                                       float* __restrict__ slog,
                                                       float* __restrict__ elog,
                                                       float* __restrict__ muS,
                                                       float* __restrict__ rstdS,
                                                       float* __restrict__ muE,
                                                       float* __restrict__ rstdE) {
  __shared__ float red[4];
  const int row = blockIdx.x, tid = threadIdx.x;
  const int br = blockIdx.y;
  const float* Hb = br ? HbE : HbS;
  const float* g = br ? gE : gS;
  const float* beta = br ? betaE : betaS;
  const float* w = br ? wE : wS;
  const float* bsc = br ? bE : bS;
  const float* h = Hb + (size_t)row * FF;

  float4 v[3];
  float s = 0.0f;
  #pragma unroll
  for (int t = 0; t < 3; t++) {
    v[t] = *(const float4*)(h + tid * 4 + t * 1024);
    s += v[t].x + v[t].y + v[t].z + v[t].w;
  }
  float mu = block_reduce_256(s, red) * (1.0f / (float)FF);

  float s2 = 0.0f;
  #pragma unroll
  for (int t = 0; t < 3; t++) {
    float dx = v[t].x - mu, dy = v[t].y - mu, dz = v[t].z - mu, dw = v[t].w - mu;
    s2 += dx * dx + dy * dy + dz * dz + dw * dw;
  }
  float var = block_reduce_256(s2, red) * (1.0f / (float)FF);
  float rstd = rsqrtf(var + 1e-5f);

  float dot = 0.0f;
  #pragma unroll
  for (int t = 0; t < 3; t++) {
    int idx = tid * 4 + t * 1024;
    float4 gv = *(const float4*)(g + idx);
    float4 bv = *(const float4*)(beta + idx);
    float4 wv = *(const float4*)(w + idx);
    float rx = (v[t].x - mu) * rstd * gv.x + bv.x;
    float ry = (v[t].y - mu) * rstd * gv.y + bv.y;
    float rz = (v[t].z - mu) * rstd * gv.z + bv.z;
    float rw = (v[t].w - mu) * rstd * gv.w + bv.w;
    dot += rx * wv.x + ry * wv.y + rz * wv.z + rw * wv.w;
  }
  float dt = block_reduce_256(dot, red);
  if (tid == 0) {
    if (br) { elog[row] = dt + bsc[0]; muE[row] = mu; rstdE[row] = rstd; }
    else    { slog[row] = dt + bsc[0]; muS[row] = mu; rstdS[row] = rstd; }
  }
}

// ---------------- band joint (inline E-LayerNorm, fused junk sum + 16-bit key histogram) ----------------

__global__ __launch_bounds__(256) void band_joint_kernel(const float* __restrict__ T,
                                                         const float* __restrict__ Eraw,
                                                         const float* __restrict__ muE,
                                                         const float* __restrict__ rstdE,
                                                         const float* __restrict__ gE,
                                                         const float* __restrict__ betaE,
                                                         const float* __restrict__ sl,
                                                         const float* __restrict__ el,
                                                         float* __restrict__ band,
                                                         double* __restrict__ jacc,
                                                         unsigned* __restrict__ hist16) {
  __shared__ float Elds[45][260];   // 260 = 256 + 4 pad
  __shared__ float red[4];
  const int t = threadIdx.x;
  const int bx = blockIdx.x;
  const int sbx = (bx & 7) * 32 + (bx >> 3);   // XCD-locality swizzle (perf heuristic)
  const int i0 = sbx * 16;
  const int r_l = t >> 4, c = t & 15;

  float accd[MAXSPAN];
  #pragma unroll
  for (int d = 0; d < MAXSPAN; d++) accd[d] = 0.0f;

  for (int k0 = 0; k0 < FF; k0 += 256) {
    const float* trow = T + (size_t)(i0 + r_l) * FF + k0 + c * 16;
    float4 tv0 = *(const float4*)(trow + 0);
    float4 tv1 = *(const float4*)(trow + 4);
    float4 tv2 = *(const float4*)(trow + 8);
    float4 tv3 = *(const float4*)(trow + 12);
    __syncthreads();
    for (int rr = t >> 6; rr < 45; rr += 4) {
      int gr = i0 + rr;
      int cc = (t & 63) * 4;
      float4 rv = {0.f, 0.f, 0.f, 0.f};
      if (gr < S) {
        float4 ev = *(const float4*)(Eraw + (size_t)gr * FF + k0 + cc);
        float m = muE[gr], rs = rstdE[gr];
        float4 gv = *(const float4*)(gE + k0 + cc);
        float4 bv = *(const float4*)(betaE + k0 + cc);
        rv.x = (ev.x - m) * rs * gv.x + bv.x;
        rv.y = (ev.y - m) * rs * gv.y + bv.y;
        rv.z = (ev.z - m) * rs * gv.z + bv.z;
        rv.w = (ev.w - m) * rs * gv.w + bv.w;
      }
      *(float4*)&Elds[rr][cc] = rv;
    }
    __syncthreads();
    #pragma unroll
    for (int d = 0; d < MAXSPAN; d++) {
      const float* er = &Elds[r_l + d][c * 16];
      float4 e0 = *(const float4*)(er + 0);
      float4 e1 = *(const float4*)(er + 4);
      float4 e2 = *(const float4*)(er + 8);
      float4 e3 = *(const float4*)(er + 12);
      accd[d] += tv0.x * e0.x + tv0.y * e0.y + tv0.z * e0.z + tv0.w * e0.w
               + tv1.x * e1.x + tv1.y * e1.y + tv1.z * e1.z + tv1.w * e1.w
               + tv2.x * e2.x + tv2.y * e2.y + tv2.z * e2.z + tv2.w * e2.w
               + tv3.x * e3.x + tv3.y * e3.y + tv3.z * e3.z + tv3.w * e3.w;
    }
  }

  const int i = i0 + r_l;
  const float my_sl = sl[i];
  float jsum = 0.0f;
  #pragma unroll
  for (int d = 0; d < MAXSPAN; d++) {
    float v = accd[d];
    v += __shfl_down(v, 8, 16);
    v += __shfl_down(v, 4, 16);
    v += __shfl_down(v, 2, 16);
    v += __shfl_down(v, 1, 16);
    if (c == 0) {
      int j = i + d;
      if (j < S) {
        float vv = v + my_sl + el[j];
        vv = fminf(fmaxf(vv, -10000.0f), 10000.0f);
        band[i * MAXSPAN + d] = vv;
        atomicAdd(&hist16[f2key(vv) >> 16], 1u);
        float p = 1.0f / (1.0f + expf(-vv));
        jsum += fmaxf(logf(1.0f - p), -100.0f);
      } else {
        band[i * MAXSPAN + d] = -1e30f;
      }
    }
  }
  float tot = block_reduce_256(jsum, red);
  if (t == 0) atomicAdd(jacc, (double)tot);
}

// ---------------- top-k + cost finalize (single block; parallelized) ----------------
// (a) uint4 histogram sum, (b) LDS-staged threshold-bin scan, (c) parallel
// bitonic sort of the threshold-tie set. Selection semantics identical:
// descending full-key, ties ascending index.

__global__ __launch_bounds__(1024) void topk_finalize_kernel(const float* __restrict__ band,
                                                             const int* __restrict__ gold,
                                                             const double* __restrict__ jacc,
                                                             const unsigned* __restrict__ hist16,
                                                             float* __restrict__ out) {
  __shared__ int csum[1024];
  __shared__ unsigned sh_T16;
  __shared__ int sh_remk;
  __shared__ int sh_chunk, sh_above;
  __shared__ unsigned hbin[64];
  __shared__ int idxbuf[1024];
  __shared__ unsigned tkey[256];
  __shared__ int tidx[256];
  __shared__ int cnt_gt, cnt_eq;
  __shared__ int sb[1024];
  __shared__ int gcell[G];
  __shared__ float redf[16];
  const int tid = threadIdx.x;

  // ---- threshold from 65536-bin histogram (vectorized sum) ----
  int s = 0;
  {
    const uint4* hv = (const uint4*)hist16 + (size_t)tid * 16;
    #pragma unroll
    for (int q = 0; q < 16; q++) {
      uint4 u = hv[q];
      s += (int)(u.x + u.y + u.z + u.w);
    }
  }
  csum[tid] = s;
  if (tid < 256) { tkey[tid] = 0u; tidx[tid] = 0x7FFFFFFF; }   // padding for bitonic
  __syncthreads();
  // suffix sum (Hillis-Steele): csum[t] = sum over chunks >= t
  for (int off = 1; off < 1024; off <<= 1) {
    int v = (tid + off < 1024) ? csum[tid + off] : 0;
    __syncthreads();
    csum[tid] += v;
    __syncthreads();
  }
  // csum non-increasing; find chunk containing the rank-MAXK crossing
  {
    int nxt = (tid < 1023) ? csum[tid + 1] : 0;
    if (csum[tid] >= MAXK && nxt < MAXK) { sh_chunk = tid; sh_above = nxt; }
  }
  __syncthreads();
  if (tid < 64) hbin[tid] = hist16[sh_chunk * 64 + tid];
  __syncthreads();
  if (tid == 0) {
    int cum = sh_above;            // count strictly above chunk's top bin range
    int b = 63;
    for (;; b--) {
      int h = (int)hbin[b];
      if (cum + h >= MAXK || b == 0) { sh_T16 = (unsigned)(sh_chunk * 64 + b); sh_remk = MAXK - cum; break; }
      cum += h;
    }
  }
  __syncthreads();
  const unsigned T16 = sh_T16;
  int remk = sh_remk;

  // ---- collect ----
  if (tid == 0) { cnt_gt = 0; cnt_eq = 0; }
  __syncthreads();
  for (int e = tid; e < NBAND; e += 1024) {
    unsigned key = f2key(band[e]);
    unsigned k16 = key >> 16;
    if (k16 >= T16) {
      int i = e / MAXSPAN, d = e - i * MAXSPAN;
      int fi = i * S + i + d;
      if (k16 > T16) {
        int p = atomicAdd(&cnt_gt, 1);
        if (p < 1024) idxbuf[p] = fi;
      } else {
        int p = atomicAdd(&cnt_eq, 1);
        if (p < 256) { tkey[p] = key; tidx[p] = fi; }
      }
    }
  }
  __syncthreads();

  // ---- parallel bitonic sort of the tie set (desc key, ties asc idx) ----
  for (int ksz2 = 2; ksz2 <= 256; ksz2 <<= 1) {
    for (int jj = ksz2 >> 1; jj > 0; jj >>= 1) {
      if (tid < 256) {
        int ixj = tid ^ jj;
        if (ixj > tid) {
          unsigned ka = tkey[tid], kb = tkey[ixj];
          int ia = tidx[tid], ib = tidx[ixj];
          bool aFirst = (ka > kb) || (ka == kb && ia < ib);
          bool up = ((tid & ksz2) == 0);
          if (up ? !aFirst : aFirst) {
            tkey[tid] = kb; tidx[tid] = ib;
            tkey[ixj] = ka; tidx[ixj] = ia;
          }
        }
      }
      __syncthreads();
    }
  }
  {
    int ngt = cnt_gt < 1024 ? cnt_gt : 1024;
    int ne = cnt_eq < 256 ? cnt_eq : 256;
    int take = remk < ne ? remk : ne;
    if (tid < take && ngt + tid < 1024) idxbuf[ngt + tid] = tidx[tid];
  }
  __syncthreads();

  // ---- bitonic sort of the MAXK indices (ascending) ----
  sb[tid] = (tid < MAXK) ? idxbuf[tid] : 0x7FFFFFFF;
  __syncthreads();
  for (int ksz = 2; ksz <= 1024; ksz <<= 1) {
    for (int jj = ksz >> 1; jj > 0; jj >>= 1) {
      int ixj = tid ^ jj;
      if (ixj > tid) {
        int a2 = sb[tid], b2 = sb[ixj];
        bool up = ((tid & ksz) == 0);
        if (up ? (a2 > b2) : (a2 < b2)) { sb[tid] = b2; sb[ixj] = a2; }
      }
      __syncthreads();
    }
  }
  if (tid < MAXK) {
    int fi = sb[tid];
    out[O_START + tid] = (float)(fi >> 12);
    out[O_END + tid]   = (float)(fi & 4095);
    out[O_MASK + tid]  = 1.0f;
  }

  // ---- cost finalize ----
  if (tid < G) {
    int gs = gold[2 * tid], ge = gold[2 * tid + 1];
    gcell[tid] = gs * MAXSPAN + (ge - gs);
  }
  __syncthreads();
  float tg = 0.0f, tj = 0.0f;
  if (tid < G) {
    int cell = gcell[tid];
    float x = band[cell];
    float p = 1.0f / (1.0f + expf(-x));
    tg = fmaxf(logf(p), -100.0f);
    bool first = true;
    for (int q = 0; q < tid; q++)
      if (gcell[q] == cell) { first = false; break; }
    if (first) tj = fmaxf(logf(1.0f - p), -100.0f);
  }
  float sg = block_reduce_1024(tg, redf);
  float sj = block_reduce_1024(tj, redf);
  if (tid == 0) {
    double junk = *jacc - (double)sj;   // exclude gold cells (set to 0 in reference)
    double cost = -((double)sg / (double)G) - (junk / BAND_COUNT);
    out[O_COST] = (float)cost;
  }
}

// ---------------- launch ----------------

extern "C" void kernel_launch(void* const* d_in, const int* in_sizes, int n_in,
                              void* d_out, int out_size, void* d_ws, size_t ws_size,
                              hipStream_t stream) {
  (void)in_sizes; (void)n_in; (void)out_size; (void)ws_size;
  const float* seq    = (const float*)d_in[0];
  const int*   gold   = (const int*)d_in[2];
  const float* W_sm   = (const float*)d_in[3];
  const float* b_sm   = (const float*)d_in[4];
  const float* g_sm   = (const float*)d_in[5];
  const float* be_sm  = (const float*)d_in[6];
  const float* W_em   = (const float*)d_in[7];
  const float* b_em   = (const float*)d_in[8];
  const float* g_em   = (const float*)d_in[9];
  const float* be_em  = (const float*)d_in[10];
  const float* w_st   = (const float*)d_in[11];
  const float* b_st   = (const float*)d_in[12];
  const float* w_en   = (const float*)d_in[13];
  const float* b_en   = (const float*)d_in[14];
  const float* W_s2e  = (const float*)d_in[15];
  const float* b_s2e  = (const float*)d_in[16];
  float* out = (float*)d_out;
  char* ws = (char*)d_ws;

  const size_t SZ_REP = (size_t)S * FF * 4;          // 50331648
  float*  bufS = (float*)(ws);                       // h_start f32 (gelu out, pre-LN)
  float*  bufE = (float*)(ws + SZ_REP);              // h_end f32 (gelu out, pre-LN)
  float*  bufT = (float*)(ws + 2 * SZ_REP);          // temp f32
  // R3: seq hi/lo tiled during GEMM1/2; reused as a3 (normalized start) hi/lo tiled
  char* R3 = ws + 3 * SZ_REP;
  unsigned short* seqhi = (unsigned short*)R3;
  unsigned short* seqlo = (unsigned short*)(R3 + (size_t)S * H * 2);
  unsigned short* a3hi  = (unsigned short*)R3;
  unsigned short* a3lo  = (unsigned short*)(R3 + (size_t)S * FF * 2);
  // R4: tiled weights. Phase 1: wb1/wb2 (H x FF). Phase 2: wb (FF x FF).
  char* R4 = ws + 4 * SZ_REP;
  const size_t SZ_W12 = (size_t)H * FF * 2;          // 6291456
  unsigned short* wb1hi = (unsigned short*)R4;
  unsigned short* wb1lo = (unsigned short*)(R4 + SZ_W12);
  unsigned short* wb2hi = (unsigned short*)(R4 + 2 * SZ_W12);
  unsigned short* wb2lo = (unsigned short*)(R4 + 3 * SZ_W12);
  unsigned short* wbhi = (unsigned short*)R4;
  unsigned short* wblo = (unsigned short*)(R4 + (size_t)FF * FF * 2);
  // R5: small buffers
  char* R5 = R4 + 2 * (size_t)FF * FF * 2;
  float*    band   = (float*)R5;                              // NBAND f32
  unsigned* hist16 = (unsigned*)(R5 + (size_t)NBAND * 4);     // 65536 bins
  double*   jacc   = (double*)(R5 + (size_t)NBAND * 4 + 262144);
  float*    slog   = (float*)(R5 + (size_t)NBAND * 4 + 262144 + 64);
  float*  elog  = slog + S;
  float*  muS   = elog + S;
  float*  rstdS = muS + S;
  float*  muE   = rstdS + S;
  float*  rstdE = muE + S;

  // zero hist16 + jacc in one memset (jacc sits right after hist16)
  hipMemsetAsync(hist16, 0, 262144 + 64 + 8, stream);

  dim3 gg(16, 16);           // GEMM3: (FF/192, S/256)
  dim3 gg2(16, 16, 2);       // fused GEMM1+2

  // head pack: seq (tiled hi/lo + passthrough copy to out) + both H x FF weights
  pack_head_kernel<<<dim3(32, 320), 256, 0, stream>>>(seq, out + O_SEQ, seqhi, seqlo,
                                                      W_sm, W_em, wb1hi, wb1lo, wb2hi, wb2lo);
  // fused GEMM1+2 (gelu epilogue, 8-wave pipeline)
  gemm_mfma_dual_kernel<<<gg2, 512, 0, stream>>>(seqhi, seqlo, wb1hi, wb1lo, wb2hi, wb2lo,
                                                 b_sm, b_em, bufS, bufE, FF, H);
  // LN stats + logits for both branches, no writeback
  ln_stats_kernel<<<dim3(S, 2), 256, 0, stream>>>(bufS, bufE, g_sm, be_sm, w_st, b_st,
                                                  g_em, be_em, w_en, b_en,
                                                  slog, elog, muS, rstdS, muE, rstdE);
  // mid pack: LN-fused start pack (coalesced) + W_s2e pack in one dispatch
  pack_mid_kernel<<<dim3(96, 224), 256, 0, stream>>>(bufS, muS, rstdS, g_sm, be_sm,
                                                     a3hi, a3lo, W_s2e, wbhi, wblo);
  // GEMM3 (8-wave pipeline)
  gemm_mfma_kernel<<<gg, 512, 0, stream>>>(a3hi, a3lo, wbhi, wblo, b_s2e, bufT, FF, FF);

  // band joint with inline E-LayerNorm + fused junk-cost + 16-bit key histogram
  band_joint_kernel<<<S / 16, 256, 0, stream>>>(bufT, bufE, muE, rstdE, g_em, be_em,
                                                slog, elog, band, jacc, hist16);

  // top-k (threshold from hist) + cost finalize
  topk_finalize_kernel<<<1, 1024, 0, stream>>>(band, gold, jacc, hist16, out);
}